// Round 20
// baseline (225.288 us; speedup 1.0000x reference)
//
#include <hip/hip_runtime.h>
#include <hip/hip_bf16.h>

// Problem constants
#define SB 2048
#define DB 512
#define HB 8
#define DKB 64
#define DFB 2048
#define BATCH 4
#define BSTR 92   // band/P LDS row stride in shorts (184B: 14 dw mod 32, gcd 2)

typedef __attribute__((ext_vector_type(8))) short bf16x8;
typedef __attribute__((ext_vector_type(4))) float f32x4;
typedef __attribute__((ext_vector_type(2))) float f32x2;
typedef __attribute__((ext_vector_type(2))) unsigned u32x2;
typedef __attribute__((ext_vector_type(4))) unsigned u32x4;
typedef __attribute__((ext_vector_type(4))) short s16x4;

static __device__ __forceinline__ short f2bf(float x) {
  union { float f; unsigned u; } v; v.f = x;
  unsigned r = (v.u + 0x7fffu + ((v.u >> 16) & 1u)) >> 16;
  return (short)(unsigned short)r;
}

static __device__ __forceinline__ float bflo(unsigned u) {
  union { unsigned x; float f; } v; v.x = u << 16; return v.f;
}
static __device__ __forceinline__ float bfhi(unsigned u) {
  union { unsigned x; float f; } v; v.x = u & 0xffff0000u; return v.f;
}

static __device__ __forceinline__ unsigned pack2bf(float a, float b) {
  return (unsigned)(unsigned short)f2bf(a) | ((unsigned)(unsigned short)f2bf(b) << 16);
}

static __device__ __forceinline__ f32x4 mfma16(bf16x8 a, bf16x8 b, f32x4 c) {
  return __builtin_amdgcn_mfma_f32_16x16x32_bf16(a, b, c, 0, 0, 0);
}

// raw hardware 2^x (v_exp_f32); exp2f() is the precise libm path (R16 regr.)
static __device__ __forceinline__ float fexp2(float x) {
#if __has_builtin(__builtin_amdgcn_exp2f)
  return __builtin_amdgcn_exp2f(x);
#else
  float r;
  asm("v_exp_f32 %0, %1" : "=v"(r) : "v"(x));
  return r;
#endif
}

// async global->LDS, 16B per lane; LDS dest is wave-uniform base + lane*16
static __device__ __forceinline__ void gload_lds16(const short* g, short* l) {
  __builtin_amdgcn_global_load_lds(
      (const __attribute__((address_space(1))) unsigned*)g,
      (__attribute__((address_space(3))) unsigned*)l, 16, 0, 0);
}

// ---------------- weight prep ----------------
__global__ __launch_bounds__(256) void conv_kernel(const float* __restrict__ src,
                                                   short* __restrict__ dst, int n) {
  int i = blockIdx.x * 256 + threadIdx.x;
  if (i < n) dst[i] = f2bf(src[i]);
}

// dst[n*K + k] = src[k*N + n] * scale  -- 64x64 LDS-tiled transpose
__global__ __launch_bounds__(256) void tconv_kernel(const float* __restrict__ src,
                                                    short* __restrict__ dst,
                                                    int K, int N, float scale) {
  __shared__ float t[64][65];
  int n0 = blockIdx.x * 64, k0 = blockIdx.y * 64;
  int cn = threadIdx.x & 63, rk = threadIdx.x >> 6;
#pragma unroll
  for (int r = 0; r < 16; ++r)
    t[rk + r * 4][cn] = src[(size_t)(k0 + rk + r * 4) * N + n0 + cn];
  __syncthreads();
#pragma unroll
  for (int r = 0; r < 16; ++r)
    dst[(size_t)(n0 + rk + r * 4) * K + k0 + cn] = f2bf(t[cn][rk + r * 4] * scale);
}

// 4x 512x512 transposes in one launch. wq scaled by log2(e).
__global__ __launch_bounds__(256) void tconv4_kernel(
    const float* __restrict__ s0, const float* __restrict__ s1,
    const float* __restrict__ s2, const float* __restrict__ s3,
    short* __restrict__ dst) {
  __shared__ float t[64][65];
  int z = blockIdx.z;
  const float* src = z == 0 ? s0 : (z == 1 ? s1 : (z == 2 ? s2 : s3));
  float scale = (z == 0) ? 1.4426950408889634f : ((z == 1) ? 0.125f : 1.f);
  short* d = dst + (size_t)z * 512 * 512;
  int n0 = blockIdx.x * 64, k0 = blockIdx.y * 64;
  int cn = threadIdx.x & 63, rk = threadIdx.x >> 6;
#pragma unroll
  for (int r = 0; r < 16; ++r)
    t[rk + r * 4][cn] = src[(size_t)(k0 + rk + r * 4) * 512 + n0 + cn];
  __syncthreads();
#pragma unroll
  for (int r = 0; r < 16; ++r)
    d[(size_t)(n0 + rk + r * 4) * 512 + k0 + cn] = f2bf(t[cn][rk + r * 4] * scale);
}

// ---------------- layernorm: one wave per 512-elem row ----------------
__global__ __launch_bounds__(256) void ln_kernel(const float* __restrict__ in,
                                                 const float* __restrict__ g,
                                                 const float* __restrict__ bb,
                                                 short* __restrict__ out) {
  int w = threadIdx.x >> 6, l = threadIdx.x & 63;
  size_t row = (size_t)blockIdx.x * 4 + w;
  const float* xr = in + row * DB;
  f32x4 v0 = *(const f32x4*)(xr + l * 8);
  f32x4 v1 = *(const f32x4*)(xr + l * 8 + 4);
  float s = (v0[0] + v0[1]) + (v0[2] + v0[3]) + (v1[0] + v1[1]) + (v1[2] + v1[3]);
  float s2 = (v0[0] * v0[0] + v0[1] * v0[1]) + (v0[2] * v0[2] + v0[3] * v0[3]) +
             (v1[0] * v1[0] + v1[1] * v1[1]) + (v1[2] * v1[2] + v1[3] * v1[3]);
#pragma unroll
  for (int off = 1; off < 64; off <<= 1) {
    s += __shfl_xor(s, off, 64);
    s2 += __shfl_xor(s2, off, 64);
  }
  float mean = s * (1.f / DB);
  float var = s2 * (1.f / DB) - mean * mean;
  float rstd = rsqrtf(var + 1e-6f);
  f32x4 g0 = *(const f32x4*)(g + l * 8);
  f32x4 g1 = *(const f32x4*)(g + l * 8 + 4);
  f32x4 b0 = *(const f32x4*)(bb + l * 8);
  f32x4 b1 = *(const f32x4*)(bb + l * 8 + 4);
  bf16x8 ov;
#pragma unroll
  for (int e = 0; e < 4; ++e) ov[e] = f2bf((v0[e] - mean) * rstd * g0[e] + b0[e]);
#pragma unroll
  for (int e = 0; e < 4; ++e) ov[4 + e] = f2bf((v1[e] - mean) * rstd * g1[e] + b1[e]);
  *(bf16x8*)(out + row * DB + l * 8) = ov;
}

// ---------------- GEMM 128x128, BK=32 double-buffered + 4-chunk swizzle ---
template <int KD, int EPI>
__global__ __launch_bounds__(256) void gemm_kernel(
    const short* __restrict__ A, const short* __restrict__ BT,
    const float* __restrict__ bias, const float* __restrict__ resid,
    short* __restrict__ o0, short* __restrict__ o1, short* __restrict__ o2,
    float* __restrict__ of) {
  __shared__ short As[2][4096];  // 128 rows x 32 k
  __shared__ short Bs[2][4096];
  int tid = threadIdx.x;
  int l = tid & 63, w = tid >> 6;
  int wr = w >> 1, wc = w & 1;
  int lr = l & 15, lq = l >> 4;
  int row0 = blockIdx.y * 128;
  int col0 = blockIdx.x * 128;

  f32x4 acc[4][4];
#pragma unroll
  for (int a = 0; a < 4; ++a)
#pragma unroll
    for (int b = 0; b < 4; ++b) acc[a][b] = (f32x4){0.f, 0.f, 0.f, 0.f};

  int srow = tid >> 2;                   // [0,64); also stages srow+64
  int scol = (tid & 3) ^ (srow & 3);     // inverse-swizzled source chunk
  const short* gA = A + (size_t)(row0 + srow) * KD + scol * 8;
  const short* gB = BT + (size_t)(col0 + srow) * KD + scol * 8;
  const size_t step64 = (size_t)64 * KD;
  int woff = w * 512;

  auto stage = [&](int buf, int k0) {
    gload_lds16(gA + k0, As[buf] + woff);
    gload_lds16(gA + step64 + k0, As[buf] + woff + 2048);
    gload_lds16(gB + k0, Bs[buf] + woff);
    gload_lds16(gB + step64 + k0, Bs[buf] + woff + 2048);
  };

  stage(0, 0);
  __syncthreads();
  int cur = 0;
  for (int k0 = 0; k0 < KD; k0 += 32) {
    if (k0 + 32 < KD) stage(cur ^ 1, k0 + 32);  // prefetch next tile
    bf16x8 af[4], bfv[4];
#pragma unroll
    for (int a = 0; a < 4; ++a) {
      int rk = wr * 64 + a * 16 + lr;
      af[a] = *(const bf16x8*)(As[cur] + rk * 32 + ((lq ^ (rk & 3)) << 3));
    }
#pragma unroll
    for (int b = 0; b < 4; ++b) {
      int rk = wc * 64 + b * 16 + lr;
      bfv[b] = *(const bf16x8*)(Bs[cur] + rk * 32 + ((lq ^ (rk & 3)) << 3));
    }
#pragma unroll
    for (int a = 0; a < 4; ++a)
#pragma unroll
      for (int b = 0; b < 4; ++b)
        acc[a][b] = mfma16(af[a], bfv[b], acc[a][b]);
    __syncthreads();
    cur ^= 1;
  }

#pragma unroll
  for (int a = 0; a < 4; ++a)
#pragma unroll
    for (int b = 0; b < 4; ++b) {
      size_t colb = (size_t)col0 + wc * 64 + b * 16 + lr;
      if (EPI == 0 && (int)(colb >> 9) == 2) {
        int d = (int)(colb & 63);
        size_t rowb = (size_t)row0 + wr * 64 + a * 16 + lq * 4;
        size_t b_ = rowb >> 11, s_ = rowb & 2047;
        size_t bh = b_ * HB + (int)((colb >> 6) & 7);
        s16x4 pkv;
#pragma unroll
        for (int r = 0; r < 4; ++r) pkv[r] = f2bf(acc[a][b][r]);
        *(s16x4*)(o2 + (bh * DKB + d) * SB + s_) = pkv;
        continue;
      }
#pragma unroll
      for (int r = 0; r < 4; ++r) {
        size_t row = (size_t)row0 + wr * 64 + a * 16 + lq * 4 + r;
        size_t col = colb;
        float val = acc[a][b][r];
        if (EPI == 0) {
          int sect = (int)(col >> 9);
          int hh = (int)((col >> 6) & 7);
          int d = (int)(col & 63);
          size_t b_ = row >> 11, s_ = row & 2047;
          size_t bh = b_ * HB + hh;
          short bv = f2bf(val);
          if (sect == 0) o0[(bh * SB + s_) * DKB + d] = bv;
          else o1[(bh * SB + s_) * DKB + d] = bv;
        } else if (EPI == 1) {
          of[row * DB + col] = resid[row * DB + col] + val + bias[col];
        } else {
          float tv = val + bias[col];
          o0[row * DFB + col] = f2bf(tv > 0.f ? tv : 0.f);
        }
      }
    }
}

// ---------------- GEMM 128x64, BK=32 dbuf + swizzle (O-proj, FF2) --------
template <int KD>
__global__ __launch_bounds__(256) void gemm64_kernel(
    const short* __restrict__ A, const short* __restrict__ BT,
    const float* __restrict__ bias, const float* __restrict__ resid,
    float* __restrict__ of) {
  __shared__ short As[2][4096];  // 128 x 32
  __shared__ short Bs[2][2048];  // 64 x 32
  int tid = threadIdx.x;
  int l = tid & 63, w = tid >> 6;
  int lr = l & 15, lq = l >> 4;
  int row0 = blockIdx.y * 128;
  int col0 = blockIdx.x * 64;

  f32x4 acc[2][4];
#pragma unroll
  for (int a = 0; a < 2; ++a)
#pragma unroll
    for (int b = 0; b < 4; ++b) acc[a][b] = (f32x4){0.f, 0.f, 0.f, 0.f};

  int srow = tid >> 2;
  int scol = (tid & 3) ^ (srow & 3);
  const short* gA = A + (size_t)(row0 + srow) * KD + scol * 8;
  const short* gB = BT + (size_t)(col0 + srow) * KD + scol * 8;
  const size_t step64 = (size_t)64 * KD;
  int woff = w * 512;

  auto stage = [&](int buf, int k0) {
    gload_lds16(gA + k0, As[buf] + woff);
    gload_lds16(gA + step64 + k0, As[buf] + woff + 2048);
    gload_lds16(gB + k0, Bs[buf] + woff);
  };

  stage(0, 0);
  __syncthreads();
  int cur = 0;
  for (int k0 = 0; k0 < KD; k0 += 32) {
    if (k0 + 32 < KD) stage(cur ^ 1, k0 + 32);
    bf16x8 af[2], bfv[4];
#pragma unroll
    for (int a = 0; a < 2; ++a) {
      int rk = w * 32 + a * 16 + lr;
      af[a] = *(const bf16x8*)(As[cur] + rk * 32 + ((lq ^ (rk & 3)) << 3));
    }
#pragma unroll
    for (int b = 0; b < 4; ++b) {
      int rk = b * 16 + lr;
      bfv[b] = *(const bf16x8*)(Bs[cur] + rk * 32 + ((lq ^ (rk & 3)) << 3));
    }
#pragma unroll
    for (int a = 0; a < 2; ++a)
#pragma unroll
      for (int b = 0; b < 4; ++b)
        acc[a][b] = mfma16(af[a], bfv[b], acc[a][b]);
    __syncthreads();
    cur ^= 1;
  }

#pragma unroll
  for (int a = 0; a < 2; ++a)
#pragma unroll
    for (int b = 0; b < 4; ++b)
#pragma unroll
      for (int r = 0; r < 4; ++r) {
        size_t row = (size_t)row0 + w * 32 + a * 16 + lq * 4 + r;
        size_t col = (size_t)col0 + b * 16 + lr;
        of[row * DB + col] = resid[row * DB + col] + acc[a][b][r] + bias[col];
      }
}

// ---------------- attention helpers ----------------
static __device__ __forceinline__ void e_phase_lds(const short* Ebuf, int w, int ph,
                                                   bf16x8 q0, bf16x8 q1,
                                                   short* bdx, int lr, int lq) {
  bf16x8 ef[10];
#pragma unroll
  for (int nt = 0; nt < 5; ++nt) {
    int re = 48 - 16 * w + nt * 16 + lr;
    int sr = (re + ph) & 127;
    const short* eb = Ebuf + sr * 64;
    ef[nt * 2] = *(const bf16x8*)(eb + ((lq ^ (sr & 7)) << 3));
    ef[nt * 2 + 1] = *(const bf16x8*)(eb + (((lq + 4) ^ (sr & 7)) << 3));
  }
  const f32x4 zz = {0.f, 0.f, 0.f, 0.f};
#pragma unroll
  for (int nt = 0; nt < 5; ++nt) {
    f32x4 rr = mfma16(ef[nt * 2 + 1], q1, mfma16(ef[nt * 2], q0, zz));
    u32x2 pk = {pack2bf(rr[0], rr[1]), pack2bf(rr[2], rr[3])};
    *(u32x2*)((char*)bdx + lr * (BSTR * 2) + (nt * 16 + lq * 4) * 2) = pk;
  }
}

// Defer-max softmax (2^x via raw v_exp; Q carries log2e). Vector band gather.
static __device__ __forceinline__ void sm_step(const f32x4* sc, const short* bd,
                                               short* pb, f32x4* acc,
                                               float& mrun, float& lsum,
                                               int i0, int j0, int lr, int lq) {
  int bbase = lq * 4 + 15 - lr;
  int o = bbase & 3;
  unsigned shb = (unsigned)(o & 1) * 16;
  bool hi2 = (o >= 2);
  float bv[4][4];
#pragma unroll
  for (int hh = 0; hh < 4; ++hh) {
    int w0 = (hh * 16 + bbase) & ~3;
    const unsigned* p = (const unsigned*)(bd + lr * BSTR + w0);
    unsigned W0 = p[0], W1 = p[1], W2 = p[2], W3 = p[3];
    unsigned X0 = hi2 ? W1 : W0;
    unsigned X1 = hi2 ? W2 : W1;
    unsigned X2 = hi2 ? W3 : W2;
    unsigned out0 = (unsigned)((((unsigned long long)X1 << 32) | X0) >> shb);
    unsigned out1 = (unsigned)((((unsigned long long)X2 << 32) | X1) >> shb);
    bv[hh][0] = bflo(out0);
    bv[hh][1] = bfhi(out0);
    bv[hh][2] = bflo(out1);
    bv[hh][3] = bfhi(out1);
  }
  float s[4][4];
  if (j0 + 63 > i0) {
    int thr = i0 + lr - j0;
#pragma unroll
    for (int hh = 0; hh < 4; ++hh)
#pragma unroll
      for (int r = 0; r < 4; ++r) {
        int n = hh * 16 + lq * 4 + r;
        float v = sc[hh][r] + bv[hh][r];
        s[hh][r] = (n <= thr) ? v : -1e30f;
      }
  } else {
#pragma unroll
    for (int hh = 0; hh < 4; ++hh)
#pragma unroll
      for (int r = 0; r < 4; ++r) s[hh][r] = sc[hh][r] + bv[hh][r];
  }
  float m0 = fmaxf(fmaxf(s[0][0], s[0][1]), fmaxf(s[0][2], s[0][3]));
  float m1 = fmaxf(fmaxf(s[1][0], s[1][1]), fmaxf(s[1][2], s[1][3]));
  float m2 = fmaxf(fmaxf(s[2][0], s[2][1]), fmaxf(s[2][2], s[2][3]));
  float m3 = fmaxf(fmaxf(s[3][0], s[3][1]), fmaxf(s[3][2], s[3][3]));
  float tm = fmaxf(fmaxf(m0, m1), fmaxf(m2, m3));
  if (!__all(tm <= mrun + 8.f)) {
    float tr = fmaxf(tm, __shfl_xor(tm, 16, 64));
    tr = fmaxf(tr, __shfl_xor(tr, 32, 64));
    float mnew = fmaxf(mrun, tr);
    float corr = fexp2(mrun - mnew);
    mrun = mnew;
    lsum *= corr;
#pragma unroll
    for (int dt = 0; dt < 4; ++dt) acc[dt] *= corr;
  }
#pragma unroll
  for (int hh = 0; hh < 4; ++hh) {
    float p0 = fexp2(s[hh][0] - mrun);
    float p1 = fexp2(s[hh][1] - mrun);
    float p2 = fexp2(s[hh][2] - mrun);
    float p3 = fexp2(s[hh][3] - mrun);
    lsum += (p0 + p1) + (p2 + p3);
    u32x2 pk = {pack2bf(p0, p1), pack2bf(p2, p3)};
    int byteoff = lr * (BSTR * 2) + ((((hh << 1) | (lq >> 1)) ^ (lr & 7)) << 4) + ((lq & 1) << 3);
    *(u32x2*)((char*)pb + byteoff) = pk;
  }
}

static __device__ __forceinline__ void pv_step(const short* pb, const bf16x8* vf,
                                               f32x4* acc, int lr, int lq) {
#pragma unroll
  for (int kc = 0; kc < 2; ++kc) {
    bf16x8 pf = *(const bf16x8*)((const char*)pb + lr * (BSTR * 2) +
                                 ((((kc << 2) | lq) ^ (lr & 7)) << 4));
    __builtin_amdgcn_s_setprio(1);
#pragma unroll
    for (int dt = 0; dt < 4; ++dt)
      acc[dt] = mfma16(vf[kc * 4 + dt], pf, acc[dt]);
    __builtin_amdgcn_s_setprio(0);
  }
}

static __device__ __forceinline__ void attn_out(const f32x4* acc, float lsum,
                                                short* out, int bh, int i0,
                                                int lr, int lq) {
  float lt = lsum + __shfl_xor(lsum, 16, 64);
  lt += __shfl_xor(lt, 32, 64);
  float inv = 1.f / lt;
  int b_ = bh >> 3, hd = bh & 7;
  short* orow = out + ((size_t)(b_ * SB + i0 + lr) * DB + hd * 64);
#pragma unroll
  for (int dt = 0; dt < 4; ++dt) {
    s16x4 pkv;
#pragma unroll
    for (int r = 0; r < 4; ++r) pkv[r] = f2bf(acc[dt][r] * inv);
    *(s16x4*)(orow + dt * 16 + lq * 4) = pkv;
  }
}

// ---------------- fused causal attention with relative positions ----------
// R18 structure + sched_barrier(0) pinning the t+1 prefetch loads at the TOP
// of compute(t) (hipcc otherwise sinks consumer-less loads toward the
// barrier, destroying the T14 overlap).
__global__ __launch_bounds__(256, 2) void attn_kernel(
    const short* __restrict__ Q, const short* __restrict__ Kb,
    const short* __restrict__ VT, const short* __restrict__ Eb,
    short* __restrict__ out) {
  __shared__ short Ks[4096];
  __shared__ short Vs[4096];
  __shared__ short Elo_s[8192];     // 128-row ring
  __shared__ short Ehi_s[8192];     // 128-row ring
  __shared__ short bandP[4][2][16][BSTR];
  int tid = threadIdx.x;
  int l = tid & 63, w = tid >> 6;
  int lr = l & 15, lq = l >> 4;
  int bid = blockIdx.x;                  // 512 blocks
  int s = bid >> 3;                      // [0,64)
  int bh = (bid & 7) * 4 + (s >> 4);     // 4 heads per XCD slot
  int g = s & 15;
  int qb0 = g << 6;
  int qb1 = (31 - g) << 6;
  int i0lo = qb0 + (w << 4);
  int i0hi = qb1 + (w << 4);
  const short* Qh = Q + (size_t)bh * SB * DKB;
  const short* Kh = Kb + (size_t)bh * SB * DKB;
  const short* Vh = VT + (size_t)bh * DKB * SB;
  const short* Eh = Eb + (size_t)(bh & 7) * SB * DKB;

  bf16x8 ql0 = *(const bf16x8*)(Qh + (size_t)(i0lo + lr) * DKB + lq * 8);
  bf16x8 ql1 = *(const bf16x8*)(Qh + (size_t)(i0lo + lr) * DKB + 32 + lq * 8);
  bf16x8 qh0 = *(const bf16x8*)(Qh + (size_t)(i0hi + lr) * DKB + lq * 8);
  bf16x8 qh1 = *(const bf16x8*)(Qh + (size_t)(i0hi + lr) * DKB + 32 + lq * 8);

  int lrow = l >> 3, lch = l & 7;
  int rKV = (w << 4) + lrow;
  int cKV = lch ^ (rKV & 7);
  int cE = lch ^ lrow;                   // E swizzle: slot&7 == lrow

  const f32x4 zz = {0.f, 0.f, 0.f, 0.f};
  f32x4 accL[4], accH[4];
#pragma unroll
  for (int dt = 0; dt < 4; ++dt) { accL[dt] = zz; accH[dt] = zz; }
  float mL = -1e30f, lsL = 0.f, mH = -1e30f, lsH = 0.f;
  short* bdL = &bandP[w][0][0][0];
  short* bdH = &bandP[w][1][0][0];

  int ntrips = (qb1 >> 6) + 1;

  // ---- prologue: stage trip 0 fully via global_load_lds ----
  {
    gload_lds16(Kh + (size_t)rKV * DKB + cKV * 8, Ks + (w << 10));
    gload_lds16(Kh + (size_t)(rKV + 8) * DKB + cKV * 8, Ks + (w << 10) + 512);
    gload_lds16(Vh + (size_t)rKV * SB + cKV * 8, Vs + (w << 10));
    gload_lds16(Vh + (size_t)(rKV + 8) * SB + cKV * 8, Vs + (w << 10) + 512);
    int rbHi0 = SB - 64 - qb1;
    int phHi0 = rbHi0 & 64;
#pragma unroll
    for (int ii = 0; ii < 4; ++ii) {
      int er = rbHi0 + (w << 5) + lrow + ii * 8;
      er = er < SB ? er : SB - 1;
      int slot0 = ((w << 5) + ii * 8 + phHi0) & 127;
      gload_lds16(Eh + (size_t)er * DKB + cE * 8, Ehi_s + (slot0 << 6));
    }
    int rbLo0 = SB - 64 - qb0;
    int phLo0 = rbLo0 & 64;
#pragma unroll
    for (int ii = 0; ii < 4; ++ii) {
      int er = rbLo0 + (w << 5) + lrow + ii * 8;
      er = er < SB ? er : SB - 1;
      int slot0 = ((w << 5) + ii * 8 + phLo0) & 127;
      gload_lds16(Eh + (size_t)er * DKB + cE * 8, Elo_s + (slot0 << 6));
    }
  }
  __syncthreads();

  u32x4 rK0, rK1, rV0, rV1, rEh0, rEh1, rEl0, rEl1;

  for (int t = 0; t < ntrips; ++t) {
    int j0 = t << 6;
    int phHi = (SB - 64 - qb1 + j0) & 64;
    int phLo = (SB - 64 - qb0 + j0) & 64;
    bool pf = (t + 1 < ntrips);
    bool pfLo = (t + 1 <= g);
    // ---- issue prefetch loads for t+1 (pinned early by sched_barrier) ----
    if (pf) {
      int j0n = j0 + 64;
      rK0 = *(const u32x4*)(Kh + (size_t)(j0n + rKV) * DKB + cKV * 8);
      rK1 = *(const u32x4*)(Kh + (size_t)(j0n + rKV + 8) * DKB + cKV * 8);
      rV0 = *(const u32x4*)(Vh + (size_t)rKV * SB + j0n + cKV * 8);
      rV1 = *(const u32x4*)(Vh + (size_t)(rKV + 8) * SB + j0n + cKV * 8);
      int eb0 = SB - 64 - qb1 + j0 + 128 + (w << 4) + lrow;  // t+1 new half
      int e0 = eb0 < SB ? eb0 : SB - 1;
      int e1 = (eb0 + 8) < SB ? (eb0 + 8) : SB - 1;
      rEh0 = *(const u32x4*)(Eh + (size_t)e0 * DKB + cE * 8);
      rEh1 = *(const u32x4*)(Eh + (size_t)e1 * DKB + cE * 8);
      if (pfLo) {
        int fb0 = SB - 64 - qb0 + j0 + 128 + (w << 4) + lrow;
        int f0 = fb0 < SB ? fb0 : SB - 1;
        int f1 = (fb0 + 8) < SB ? (fb0 + 8) : SB - 1;
        rEl0 = *(const u32x4*)(Eh + (size_t)f0 * DKB + cE * 8);
        rEl1 = *(const u32x4*)(Eh + (size_t)f1 * DKB + cE * 8);
      }
    }
    __builtin_amdgcn_sched_barrier(0);  // pin load ISSUE above all compute
    // ---- compute trip t ----
    bool actLo = (t <= g);
    {
      bf16x8 kf[8];
#pragma unroll
      for (int hh = 0; hh < 4; ++hh) {
        int rk = hh * 16 + lr;
        const short* kb = Ks + rk * 64;
        kf[hh * 2] = *(const bf16x8*)(kb + ((lq ^ (rk & 7)) << 3));
        kf[hh * 2 + 1] = *(const bf16x8*)(kb + (((lq + 4) ^ (rk & 7)) << 3));
      }
      f32x4 scH[4], scL[4];
#pragma unroll
      for (int hh = 0; hh < 4; ++hh)
        scH[hh] = mfma16(kf[hh * 2 + 1], qh1, mfma16(kf[hh * 2], qh0, zz));
      if (actLo) {
#pragma unroll
        for (int hh = 0; hh < 4; ++hh)
          scL[hh] = mfma16(kf[hh * 2 + 1], ql1, mfma16(kf[hh * 2], ql0, zz));
      }
      bf16x8 vf[8];
#pragma unroll
      for (int kc = 0; kc < 2; ++kc)
#pragma unroll
        for (int dt = 0; dt < 4; ++dt) {
          int rv = dt * 16 + lr;
          vf[kc * 4 + dt] = *(const bf16x8*)(Vs + rv * 64 +
                                             (((kc * 4 + lq) ^ (rv & 7)) << 3));
        }
      e_phase_lds(Ehi_s, w, phHi, qh0, qh1, bdH, lr, lq);
      if (actLo) e_phase_lds(Elo_s, w, phLo, ql0, ql1, bdL, lr, lq);
      sm_step(scH, bdH, bdH, accH, mH, lsH, i0hi, j0, lr, lq);
      if (actLo) sm_step(scL, bdL, bdL, accL, mL, lsL, i0lo, j0, lr, lq);
      pv_step(bdH, vf, accH, lr, lq);
      if (actLo) pv_step(bdL, vf, accL, lr, lq);
    }
    // ---- write prefetched data between barriers ----
    if (pf) {
      __syncthreads();  // B: all reads of trip t done
      *(u32x4*)(Ks + (w << 10) + l * 8) = rK0;
      *(u32x4*)(Ks + (w << 10) + 512 + l * 8) = rK1;
      *(u32x4*)(Vs + (w << 10) + l * 8) = rV0;
      *(u32x4*)(Vs + (w << 10) + 512 + l * 8) = rV1;
      int s0 = ((w << 4) + phHi) & 127;        // slot of (row & 127) for t+1
      int s1 = ((w << 4) + 8 + phHi) & 127;
      *(u32x4*)(Ehi_s + (s0 << 6) + l * 8) = rEh0;
      *(u32x4*)(Ehi_s + (s1 << 6) + l * 8) = rEh1;
      if (pfLo) {
        int s2 = ((w << 4) + phLo) & 127;
        int s3 = ((w << 4) + 8 + phLo) & 127;
        *(u32x4*)(Elo_s + (s2 << 6) + l * 8) = rEl0;
        *(u32x4*)(Elo_s + (s3 << 6) + l * 8) = rEl1;
      }
      __syncthreads();  // A for trip t+1
    }
  }
  attn_out(accH, lsH, out, bh, i0hi, lr, lq);
  attn_out(accL, lsL, out, bh, i0lo, lr, lq);
}

// ---------------- host ----------------
extern "C" void kernel_launch(void* const* d_in, const int* in_sizes, int n_in,
                              void* d_out, int out_size, void* d_ws, size_t ws_size,
                              hipStream_t stream) {
  const float* x    = (const float*)d_in[0];
  const float* wq   = (const float*)d_in[2];
  const float* wk   = (const float*)d_in[3];
  const float* wv   = (const float*)d_in[4];
  const float* w0   = (const float*)d_in[5];
  const float* b0   = (const float*)d_in[6];
  const float* rel  = (const float*)d_in[7];
  const float* ln1g = (const float*)d_in[8];
  const float* ln1b = (const float*)d_in[9];
  const float* ln2g = (const float*)d_in[10];
  const float* ln2b = (const float*)d_in[11];
  const float* fw1  = (const float*)d_in[12];
  const float* fb1  = (const float*)d_in[13];
  const float* fw2  = (const float*)d_in[14];
  const float* fb2  = (const float*)d_in[15];
  float* outp = (float*)d_out;

  char* ws = (char*)d_ws;
  size_t off = 0;
  auto alloc = [&](size_t bytes) {
    char* p = ws + off;
    off += (bytes + 255) & ~(size_t)255;
    return p;
  };
  short* wqkvT = (short*)alloc((size_t)1536 * 512 * 2);  // contiguous with w0T
  short* w0T   = (short*)alloc((size_t)512 * 512 * 2);   // == wqkvT + 3*512*512
  short* fw1T  = (short*)alloc((size_t)2048 * 512 * 2);
  short* fw2T  = (short*)alloc((size_t)512 * 2048 * 2);
  short* relb  = (short*)alloc((size_t)8 * 2048 * 64 * 2);
  short* hbuf  = (short*)alloc((size_t)8192 * 512 * 2);
  short* Qb    = (short*)alloc((size_t)8192 * 512 * 2);
  short* Kbf   = (short*)alloc((size_t)8192 * 512 * 2);
  short* VTb   = (short*)alloc((size_t)8192 * 512 * 2);
  short* attnb = (short*)alloc((size_t)8192 * 512 * 2);
  float* x2    = (float*)alloc((size_t)8192 * 512 * 4);
  short* ff1 = hbuf;          // FF1 output aliases h (dead after QKV gemm)
  short* h2  = attnb;         // h2 aliases attn output (dead after O-proj)
  (void)w0T;

  dim3 blk(256);
  conv_kernel<<<(8 * 2048 * 64 + 255) / 256, blk, 0, stream>>>(rel, relb, 8 * 2048 * 64);
  tconv4_kernel<<<dim3(8, 8, 4), blk, 0, stream>>>(wq, wk, wv, w0, wqkvT);
  tconv_kernel<<<dim3(32, 8), blk, 0, stream>>>(fw1, fw1T, 512, 2048, 1.f);
  tconv_kernel<<<dim3(8, 32), blk, 0, stream>>>(fw2, fw2T, 2048, 512, 1.f);

  ln_kernel<<<2048, blk, 0, stream>>>(x, ln1g, ln1b, hbuf);
  gemm_kernel<512, 0><<<dim3(12, 64), blk, 0, stream>>>(hbuf, wqkvT, nullptr, nullptr,
                                                        Qb, Kbf, VTb, nullptr);
  attn_kernel<<<512, blk, 0, stream>>>(Qb, Kbf, VTb, relb, attnb);
  gemm64_kernel<512><<<dim3(8, 64), blk, 0, stream>>>(attnb, wqkvT + (size_t)3 * 512 * 512,
                                                      b0, x, x2);
  ln_kernel<<<2048, blk, 0, stream>>>(x2, ln2g, ln2b, h2);
  gemm_kernel<512, 2><<<dim3(16, 64), blk, 0, stream>>>(h2, fw1T, fb1, nullptr,
                                                        ff1, nullptr, nullptr, nullptr);
  gemm64_kernel<2048><<<dim3(8, 64), blk, 0, stream>>>(ff1, fw2T, fb2, x2, outp);
}

// Round 21
// 215.684 us; speedup vs baseline: 1.0445x; 1.0445x over previous
//
#include <hip/hip_runtime.h>
#include <hip/hip_bf16.h>

// Problem constants
#define SB 2048
#define DB 512
#define HB 8
#define DKB 64
#define DFB 2048
#define BATCH 4
#define BSTR 92   // band/P LDS row stride in shorts (184B: 14 dw mod 32, gcd 2)

typedef __attribute__((ext_vector_type(8))) short bf16x8;
typedef __attribute__((ext_vector_type(4))) float f32x4;
typedef __attribute__((ext_vector_type(2))) float f32x2;
typedef __attribute__((ext_vector_type(2))) unsigned u32x2;
typedef __attribute__((ext_vector_type(4))) unsigned u32x4;
typedef __attribute__((ext_vector_type(4))) short s16x4;

static __device__ __forceinline__ short f2bf(float x) {
  union { float f; unsigned u; } v; v.f = x;
  unsigned r = (v.u + 0x7fffu + ((v.u >> 16) & 1u)) >> 16;
  return (short)(unsigned short)r;
}

static __device__ __forceinline__ float bflo(unsigned u) {
  union { unsigned x; float f; } v; v.x = u << 16; return v.f;
}
static __device__ __forceinline__ float bfhi(unsigned u) {
  union { unsigned x; float f; } v; v.x = u & 0xffff0000u; return v.f;
}

static __device__ __forceinline__ unsigned pack2bf(float a, float b) {
  return (unsigned)(unsigned short)f2bf(a) | ((unsigned)(unsigned short)f2bf(b) << 16);
}

static __device__ __forceinline__ f32x4 mfma16(bf16x8 a, bf16x8 b, f32x4 c) {
  return __builtin_amdgcn_mfma_f32_16x16x32_bf16(a, b, c, 0, 0, 0);
}

// raw hardware 2^x (v_exp_f32); exp2f() is the precise libm path (R16 regr.)
static __device__ __forceinline__ float fexp2(float x) {
#if __has_builtin(__builtin_amdgcn_exp2f)
  return __builtin_amdgcn_exp2f(x);
#else
  float r;
  asm("v_exp_f32 %0, %1" : "=v"(r) : "v"(x));
  return r;
#endif
}

// async global->LDS, 16B per lane; LDS dest is wave-uniform base + lane*16
static __device__ __forceinline__ void gload_lds16(const short* g, short* l) {
  __builtin_amdgcn_global_load_lds(
      (const __attribute__((address_space(1))) unsigned*)g,
      (__attribute__((address_space(3))) unsigned*)l, 16, 0, 0);
}

// ---------------- merged prep: rel-conv + 4x weight transpose + fw1/fw2
// transpose + LN1, one launch (all input-only, mutually independent).
// Branch is block-uniform -> __syncthreads inside branches is safe.
__global__ __launch_bounds__(256) void prep_kernel(
    const float* __restrict__ rel, short* __restrict__ relb,
    const float* __restrict__ wq, const float* __restrict__ wk,
    const float* __restrict__ wv, const float* __restrict__ w0,
    short* __restrict__ wqkvT,
    const float* __restrict__ fw1, short* __restrict__ fw1T,
    const float* __restrict__ fw2, short* __restrict__ fw2T,
    const float* __restrict__ x, const float* __restrict__ ln1g,
    const float* __restrict__ ln1b, short* __restrict__ hbuf) {
  __shared__ float t[64][65];
  int b = blockIdx.x;
  int tid = threadIdx.x;
  if (b < 4096) {
    // rel conv: 8*2048*64 = 1048576 = 4096*256 exactly
    int i = b * 256 + tid;
    relb[i] = f2bf(rel[i]);
  } else if (b < 4864) {
    // transposes
    const float* src;
    short* dst;
    int K, N, n0, k0;
    float scale = 1.f;
    if (b < 4352) {  // wq/wk/wv/w0 (512x512), z = idx>>6
      int idx = b - 4096;
      int z = idx >> 6;
      src = z == 0 ? wq : (z == 1 ? wk : (z == 2 ? wv : w0));
      scale = (z == 0) ? 1.4426950408889634f : ((z == 1) ? 0.125f : 1.f);
      dst = wqkvT + (size_t)z * 512 * 512;
      K = 512; N = 512;
      n0 = (idx & 7) * 64;
      k0 = ((idx >> 3) & 7) * 64;
    } else if (b < 4608) {  // fw1: K=512, N=2048, grid (32,8)
      int idx = b - 4352;
      src = fw1; dst = fw1T; K = 512; N = 2048;
      n0 = (idx & 31) * 64;
      k0 = (idx >> 5) * 64;
    } else {                // fw2: K=2048, N=512, grid (8,32)
      int idx = b - 4608;
      src = fw2; dst = fw2T; K = 2048; N = 512;
      n0 = (idx & 7) * 64;
      k0 = (idx >> 3) * 64;
    }
    int cn = tid & 63, rk = tid >> 6;
#pragma unroll
    for (int r = 0; r < 16; ++r)
      t[rk + r * 4][cn] = src[(size_t)(k0 + rk + r * 4) * N + n0 + cn];
    __syncthreads();
#pragma unroll
    for (int r = 0; r < 16; ++r)
      dst[(size_t)(n0 + rk + r * 4) * K + k0 + cn] = f2bf(t[cn][rk + r * 4] * scale);
  } else {
    // LN1: one wave per 512-elem row, 2048 blocks
    int idx = b - 4864;
    int w = tid >> 6, l = tid & 63;
    size_t row = (size_t)idx * 4 + w;
    const float* xr = x + row * DB;
    f32x4 v0 = *(const f32x4*)(xr + l * 8);
    f32x4 v1 = *(const f32x4*)(xr + l * 8 + 4);
    float s = (v0[0] + v0[1]) + (v0[2] + v0[3]) + (v1[0] + v1[1]) + (v1[2] + v1[3]);
    float s2 = (v0[0] * v0[0] + v0[1] * v0[1]) + (v0[2] * v0[2] + v0[3] * v0[3]) +
               (v1[0] * v1[0] + v1[1] * v1[1]) + (v1[2] * v1[2] + v1[3] * v1[3]);
#pragma unroll
    for (int off = 1; off < 64; off <<= 1) {
      s += __shfl_xor(s, off, 64);
      s2 += __shfl_xor(s2, off, 64);
    }
    float mean = s * (1.f / DB);
    float var = s2 * (1.f / DB) - mean * mean;
    float rstd = rsqrtf(var + 1e-6f);
    f32x4 g0 = *(const f32x4*)(ln1g + l * 8);
    f32x4 g1 = *(const f32x4*)(ln1g + l * 8 + 4);
    f32x4 b0 = *(const f32x4*)(ln1b + l * 8);
    f32x4 b1 = *(const f32x4*)(ln1b + l * 8 + 4);
    bf16x8 ov;
#pragma unroll
    for (int e = 0; e < 4; ++e) ov[e] = f2bf((v0[e] - mean) * rstd * g0[e] + b0[e]);
#pragma unroll
    for (int e = 0; e < 4; ++e) ov[4 + e] = f2bf((v1[e] - mean) * rstd * g1[e] + b1[e]);
    *(bf16x8*)(hbuf + row * DB + l * 8) = ov;
  }
}

// ---------------- layernorm (LN2): one wave per 512-elem row --------------
__global__ __launch_bounds__(256) void ln_kernel(const float* __restrict__ in,
                                                 const float* __restrict__ g,
                                                 const float* __restrict__ bb,
                                                 short* __restrict__ out) {
  int w = threadIdx.x >> 6, l = threadIdx.x & 63;
  size_t row = (size_t)blockIdx.x * 4 + w;
  const float* xr = in + row * DB;
  f32x4 v0 = *(const f32x4*)(xr + l * 8);
  f32x4 v1 = *(const f32x4*)(xr + l * 8 + 4);
  float s = (v0[0] + v0[1]) + (v0[2] + v0[3]) + (v1[0] + v1[1]) + (v1[2] + v1[3]);
  float s2 = (v0[0] * v0[0] + v0[1] * v0[1]) + (v0[2] * v0[2] + v0[3] * v0[3]) +
             (v1[0] * v1[0] + v1[1] * v1[1]) + (v1[2] * v1[2] + v1[3] * v1[3]);
#pragma unroll
  for (int off = 1; off < 64; off <<= 1) {
    s += __shfl_xor(s, off, 64);
    s2 += __shfl_xor(s2, off, 64);
  }
  float mean = s * (1.f / DB);
  float var = s2 * (1.f / DB) - mean * mean;
  float rstd = rsqrtf(var + 1e-6f);
  f32x4 g0 = *(const f32x4*)(g + l * 8);
  f32x4 g1 = *(const f32x4*)(g + l * 8 + 4);
  f32x4 b0 = *(const f32x4*)(bb + l * 8);
  f32x4 b1 = *(const f32x4*)(bb + l * 8 + 4);
  bf16x8 ov;
#pragma unroll
  for (int e = 0; e < 4; ++e) ov[e] = f2bf((v0[e] - mean) * rstd * g0[e] + b0[e]);
#pragma unroll
  for (int e = 0; e < 4; ++e) ov[4 + e] = f2bf((v1[e] - mean) * rstd * g1[e] + b1[e]);
  *(bf16x8*)(out + row * DB + l * 8) = ov;
}

// ---------------- GEMM 128x128, BK=32 double-buffered + 4-chunk swizzle ---
template <int KD, int EPI>
__global__ __launch_bounds__(256) void gemm_kernel(
    const short* __restrict__ A, const short* __restrict__ BT,
    const float* __restrict__ bias, const float* __restrict__ resid,
    short* __restrict__ o0, short* __restrict__ o1, short* __restrict__ o2,
    float* __restrict__ of) {
  __shared__ short As[2][4096];  // 128 rows x 32 k
  __shared__ short Bs[2][4096];
  int tid = threadIdx.x;
  int l = tid & 63, w = tid >> 6;
  int wr = w >> 1, wc = w & 1;
  int lr = l & 15, lq = l >> 4;
  int row0 = blockIdx.y * 128;
  int col0 = blockIdx.x * 128;

  f32x4 acc[4][4];
#pragma unroll
  for (int a = 0; a < 4; ++a)
#pragma unroll
    for (int b = 0; b < 4; ++b) acc[a][b] = (f32x4){0.f, 0.f, 0.f, 0.f};

  int srow = tid >> 2;                   // [0,64); also stages srow+64
  int scol = (tid & 3) ^ (srow & 3);     // inverse-swizzled source chunk
  const short* gA = A + (size_t)(row0 + srow) * KD + scol * 8;
  const short* gB = BT + (size_t)(col0 + srow) * KD + scol * 8;
  const size_t step64 = (size_t)64 * KD;
  int woff = w * 512;

  auto stage = [&](int buf, int k0) {
    gload_lds16(gA + k0, As[buf] + woff);
    gload_lds16(gA + step64 + k0, As[buf] + woff + 2048);
    gload_lds16(gB + k0, Bs[buf] + woff);
    gload_lds16(gB + step64 + k0, Bs[buf] + woff + 2048);
  };

  stage(0, 0);
  __syncthreads();
  int cur = 0;
  for (int k0 = 0; k0 < KD; k0 += 32) {
    if (k0 + 32 < KD) stage(cur ^ 1, k0 + 32);  // prefetch next tile
    bf16x8 af[4], bfv[4];
#pragma unroll
    for (int a = 0; a < 4; ++a) {
      int rk = wr * 64 + a * 16 + lr;
      af[a] = *(const bf16x8*)(As[cur] + rk * 32 + ((lq ^ (rk & 3)) << 3));
    }
#pragma unroll
    for (int b = 0; b < 4; ++b) {
      int rk = wc * 64 + b * 16 + lr;
      bfv[b] = *(const bf16x8*)(Bs[cur] + rk * 32 + ((lq ^ (rk & 3)) << 3));
    }
#pragma unroll
    for (int a = 0; a < 4; ++a)
#pragma unroll
      for (int b = 0; b < 4; ++b)
        acc[a][b] = mfma16(af[a], bfv[b], acc[a][b]);
    __syncthreads();
    cur ^= 1;
  }

#pragma unroll
  for (int a = 0; a < 4; ++a)
#pragma unroll
    for (int b = 0; b < 4; ++b) {
      size_t colb = (size_t)col0 + wc * 64 + b * 16 + lr;
      if (EPI == 0 && (int)(colb >> 9) == 2) {
        int d = (int)(colb & 63);
        size_t rowb = (size_t)row0 + wr * 64 + a * 16 + lq * 4;
        size_t b_ = rowb >> 11, s_ = rowb & 2047;
        size_t bh = b_ * HB + (int)((colb >> 6) & 7);
        s16x4 pkv;
#pragma unroll
        for (int r = 0; r < 4; ++r) pkv[r] = f2bf(acc[a][b][r]);
        *(s16x4*)(o2 + (bh * DKB + d) * SB + s_) = pkv;
        continue;
      }
#pragma unroll
      for (int r = 0; r < 4; ++r) {
        size_t row = (size_t)row0 + wr * 64 + a * 16 + lq * 4 + r;
        size_t col = colb;
        float val = acc[a][b][r];
        if (EPI == 0) {
          int sect = (int)(col >> 9);
          int hh = (int)((col >> 6) & 7);
          int d = (int)(col & 63);
          size_t b_ = row >> 11, s_ = row & 2047;
          size_t bh = b_ * HB + hh;
          short bv = f2bf(val);
          if (sect == 0) o0[(bh * SB + s_) * DKB + d] = bv;
          else o1[(bh * SB + s_) * DKB + d] = bv;
        } else if (EPI == 1) {
          of[row * DB + col] = resid[row * DB + col] + val + bias[col];
        } else {
          float tv = val + bias[col];
          o0[row * DFB + col] = f2bf(tv > 0.f ? tv : 0.f);
        }
      }
    }
}

// ---------------- GEMM 128x64, BK=32 dbuf + swizzle (O-proj, FF2) --------
template <int KD>
__global__ __launch_bounds__(256) void gemm64_kernel(
    const short* __restrict__ A, const short* __restrict__ BT,
    const float* __restrict__ bias, const float* __restrict__ resid,
    float* __restrict__ of) {
  __shared__ short As[2][4096];  // 128 x 32
  __shared__ short Bs[2][2048];  // 64 x 32
  int tid = threadIdx.x;
  int l = tid & 63, w = tid >> 6;
  int lr = l & 15, lq = l >> 4;
  int row0 = blockIdx.y * 128;
  int col0 = blockIdx.x * 64;

  f32x4 acc[2][4];
#pragma unroll
  for (int a = 0; a < 2; ++a)
#pragma unroll
    for (int b = 0; b < 4; ++b) acc[a][b] = (f32x4){0.f, 0.f, 0.f, 0.f};

  int srow = tid >> 2;
  int scol = (tid & 3) ^ (srow & 3);
  const short* gA = A + (size_t)(row0 + srow) * KD + scol * 8;
  const short* gB = BT + (size_t)(col0 + srow) * KD + scol * 8;
  const size_t step64 = (size_t)64 * KD;
  int woff = w * 512;

  auto stage = [&](int buf, int k0) {
    gload_lds16(gA + k0, As[buf] + woff);
    gload_lds16(gA + step64 + k0, As[buf] + woff + 2048);
    gload_lds16(gB + k0, Bs[buf] + woff);
  };

  stage(0, 0);
  __syncthreads();
  int cur = 0;
  for (int k0 = 0; k0 < KD; k0 += 32) {
    if (k0 + 32 < KD) stage(cur ^ 1, k0 + 32);
    bf16x8 af[2], bfv[4];
#pragma unroll
    for (int a = 0; a < 2; ++a) {
      int rk = w * 32 + a * 16 + lr;
      af[a] = *(const bf16x8*)(As[cur] + rk * 32 + ((lq ^ (rk & 3)) << 3));
    }
#pragma unroll
    for (int b = 0; b < 4; ++b) {
      int rk = b * 16 + lr;
      bfv[b] = *(const bf16x8*)(Bs[cur] + rk * 32 + ((lq ^ (rk & 3)) << 3));
    }
#pragma unroll
    for (int a = 0; a < 2; ++a)
#pragma unroll
      for (int b = 0; b < 4; ++b)
        acc[a][b] = mfma16(af[a], bfv[b], acc[a][b]);
    __syncthreads();
    cur ^= 1;
  }

#pragma unroll
  for (int a = 0; a < 2; ++a)
#pragma unroll
    for (int b = 0; b < 4; ++b)
#pragma unroll
      for (int r = 0; r < 4; ++r) {
        size_t row = (size_t)row0 + w * 32 + a * 16 + lq * 4 + r;
        size_t col = (size_t)col0 + b * 16 + lr;
        of[row * DB + col] = resid[row * DB + col] + acc[a][b][r] + bias[col];
      }
}

// ---------------- attention helpers ----------------
static __device__ __forceinline__ void e_phase_lds(const short* Ebuf, int w, int ph,
                                                   bf16x8 q0, bf16x8 q1,
                                                   short* bdx, int lr, int lq) {
  bf16x8 ef[10];
#pragma unroll
  for (int nt = 0; nt < 5; ++nt) {
    int re = 48 - 16 * w + nt * 16 + lr;
    int sr = (re + ph) & 127;
    const short* eb = Ebuf + sr * 64;
    ef[nt * 2] = *(const bf16x8*)(eb + ((lq ^ (sr & 7)) << 3));
    ef[nt * 2 + 1] = *(const bf16x8*)(eb + (((lq + 4) ^ (sr & 7)) << 3));
  }
  const f32x4 zz = {0.f, 0.f, 0.f, 0.f};
#pragma unroll
  for (int nt = 0; nt < 5; ++nt) {
    f32x4 rr = mfma16(ef[nt * 2 + 1], q1, mfma16(ef[nt * 2], q0, zz));
    u32x2 pk = {pack2bf(rr[0], rr[1]), pack2bf(rr[2], rr[3])};
    *(u32x2*)((char*)bdx + lr * (BSTR * 2) + (nt * 16 + lq * 4) * 2) = pk;
  }
}

// Defer-max softmax (2^x via raw v_exp; Q carries log2e). Vector band gather.
static __device__ __forceinline__ void sm_step(const f32x4* sc, const short* bd,
                                               short* pb, f32x4* acc,
                                               float& mrun, float& lsum,
                                               int i0, int j0, int lr, int lq) {
  int bbase = lq * 4 + 15 - lr;
  int o = bbase & 3;
  unsigned shb = (unsigned)(o & 1) * 16;
  bool hi2 = (o >= 2);
  float bv[4][4];
#pragma unroll
  for (int hh = 0; hh < 4; ++hh) {
    int w0 = (hh * 16 + bbase) & ~3;
    const unsigned* p = (const unsigned*)(bd + lr * BSTR + w0);
    unsigned W0 = p[0], W1 = p[1], W2 = p[2], W3 = p[3];
    unsigned X0 = hi2 ? W1 : W0;
    unsigned X1 = hi2 ? W2 : W1;
    unsigned X2 = hi2 ? W3 : W2;
    unsigned out0 = (unsigned)((((unsigned long long)X1 << 32) | X0) >> shb);
    unsigned out1 = (unsigned)((((unsigned long long)X2 << 32) | X1) >> shb);
    bv[hh][0] = bflo(out0);
    bv[hh][1] = bfhi(out0);
    bv[hh][2] = bflo(out1);
    bv[hh][3] = bfhi(out1);
  }
  float s[4][4];
  if (j0 + 63 > i0) {
    int thr = i0 + lr - j0;
#pragma unroll
    for (int hh = 0; hh < 4; ++hh)
#pragma unroll
      for (int r = 0; r < 4; ++r) {
        int n = hh * 16 + lq * 4 + r;
        float v = sc[hh][r] + bv[hh][r];
        s[hh][r] = (n <= thr) ? v : -1e30f;
      }
  } else {
#pragma unroll
    for (int hh = 0; hh < 4; ++hh)
#pragma unroll
      for (int r = 0; r < 4; ++r) s[hh][r] = sc[hh][r] + bv[hh][r];
  }
  float m0 = fmaxf(fmaxf(s[0][0], s[0][1]), fmaxf(s[0][2], s[0][3]));
  float m1 = fmaxf(fmaxf(s[1][0], s[1][1]), fmaxf(s[1][2], s[1][3]));
  float m2 = fmaxf(fmaxf(s[2][0], s[2][1]), fmaxf(s[2][2], s[2][3]));
  float m3 = fmaxf(fmaxf(s[3][0], s[3][1]), fmaxf(s[3][2], s[3][3]));
  float tm = fmaxf(fmaxf(m0, m1), fmaxf(m2, m3));
  if (!__all(tm <= mrun + 8.f)) {
    float tr = fmaxf(tm, __shfl_xor(tm, 16, 64));
    tr = fmaxf(tr, __shfl_xor(tr, 32, 64));
    float mnew = fmaxf(mrun, tr);
    float corr = fexp2(mrun - mnew);
    mrun = mnew;
    lsum *= corr;
#pragma unroll
    for (int dt = 0; dt < 4; ++dt) acc[dt] *= corr;
  }
#pragma unroll
  for (int hh = 0; hh < 4; ++hh) {
    float p0 = fexp2(s[hh][0] - mrun);
    float p1 = fexp2(s[hh][1] - mrun);
    float p2 = fexp2(s[hh][2] - mrun);
    float p3 = fexp2(s[hh][3] - mrun);
    lsum += (p0 + p1) + (p2 + p3);
    u32x2 pk = {pack2bf(p0, p1), pack2bf(p2, p3)};
    int byteoff = lr * (BSTR * 2) + ((((hh << 1) | (lq >> 1)) ^ (lr & 7)) << 4) + ((lq & 1) << 3);
    *(u32x2*)((char*)pb + byteoff) = pk;
  }
}

static __device__ __forceinline__ void pv_step(const short* pb, const bf16x8* vf,
                                               f32x4* acc, int lr, int lq) {
#pragma unroll
  for (int kc = 0; kc < 2; ++kc) {
    bf16x8 pf = *(const bf16x8*)((const char*)pb + lr * (BSTR * 2) +
                                 ((((kc << 2) | lq) ^ (lr & 7)) << 4));
    __builtin_amdgcn_s_setprio(1);
#pragma unroll
    for (int dt = 0; dt < 4; ++dt)
      acc[dt] = mfma16(vf[kc * 4 + dt], pf, acc[dt]);
    __builtin_amdgcn_s_setprio(0);
  }
}

static __device__ __forceinline__ void attn_out(const f32x4* acc, float lsum,
                                                short* out, int bh, int i0,
                                                int lr, int lq) {
  float lt = lsum + __shfl_xor(lsum, 16, 64);
  lt += __shfl_xor(lt, 32, 64);
  float inv = 1.f / lt;
  int b_ = bh >> 3, hd = bh & 7;
  short* orow = out + ((size_t)(b_ * SB + i0 + lr) * DB + hd * 64);
#pragma unroll
  for (int dt = 0; dt < 4; ++dt) {
    s16x4 pkv;
#pragma unroll
    for (int r = 0; r < 4; ++r) pkv[r] = f2bf(acc[dt][r] * inv);
    *(s16x4*)(orow + dt * 16 + lq * 4) = pkv;
  }
}

// ---------------- fused causal attention with relative positions ----------
// R18/R20 structure: block-cooperative staging, E rings, T14 reg prefetch.
__global__ __launch_bounds__(256, 2) void attn_kernel(
    const short* __restrict__ Q, const short* __restrict__ Kb,
    const short* __restrict__ VT, const short* __restrict__ Eb,
    short* __restrict__ out) {
  __shared__ short Ks[4096];
  __shared__ short Vs[4096];
  __shared__ short Elo_s[8192];     // 128-row ring
  __shared__ short Ehi_s[8192];     // 128-row ring
  __shared__ short bandP[4][2][16][BSTR];
  int tid = threadIdx.x;
  int l = tid & 63, w = tid >> 6;
  int lr = l & 15, lq = l >> 4;
  int bid = blockIdx.x;                  // 512 blocks
  int s = bid >> 3;                      // [0,64)
  int bh = (bid & 7) * 4 + (s >> 4);     // 4 heads per XCD slot
  int g = s & 15;
  int qb0 = g << 6;
  int qb1 = (31 - g) << 6;
  int i0lo = qb0 + (w << 4);
  int i0hi = qb1 + (w << 4);
  const short* Qh = Q + (size_t)bh * SB * DKB;
  const short* Kh = Kb + (size_t)bh * SB * DKB;
  const short* Vh = VT + (size_t)bh * DKB * SB;
  const short* Eh = Eb + (size_t)(bh & 7) * SB * DKB;

  bf16x8 ql0 = *(const bf16x8*)(Qh + (size_t)(i0lo + lr) * DKB + lq * 8);
  bf16x8 ql1 = *(const bf16x8*)(Qh + (size_t)(i0lo + lr) * DKB + 32 + lq * 8);
  bf16x8 qh0 = *(const bf16x8*)(Qh + (size_t)(i0hi + lr) * DKB + lq * 8);
  bf16x8 qh1 = *(const bf16x8*)(Qh + (size_t)(i0hi + lr) * DKB + 32 + lq * 8);

  int lrow = l >> 3, lch = l & 7;
  int rKV = (w << 4) + lrow;
  int cKV = lch ^ (rKV & 7);
  int cE = lch ^ lrow;                   // E swizzle: slot&7 == lrow

  const f32x4 zz = {0.f, 0.f, 0.f, 0.f};
  f32x4 accL[4], accH[4];
#pragma unroll
  for (int dt = 0; dt < 4; ++dt) { accL[dt] = zz; accH[dt] = zz; }
  float mL = -1e30f, lsL = 0.f, mH = -1e30f, lsH = 0.f;
  short* bdL = &bandP[w][0][0][0];
  short* bdH = &bandP[w][1][0][0];

  int ntrips = (qb1 >> 6) + 1;

  // ---- prologue: stage trip 0 fully via global_load_lds ----
  {
    gload_lds16(Kh + (size_t)rKV * DKB + cKV * 8, Ks + (w << 10));
    gload_lds16(Kh + (size_t)(rKV + 8) * DKB + cKV * 8, Ks + (w << 10) + 512);
    gload_lds16(Vh + (size_t)rKV * SB + cKV * 8, Vs + (w << 10));
    gload_lds16(Vh + (size_t)(rKV + 8) * SB + cKV * 8, Vs + (w << 10) + 512);
    int rbHi0 = SB - 64 - qb1;
    int phHi0 = rbHi0 & 64;
#pragma unroll
    for (int ii = 0; ii < 4; ++ii) {
      int er = rbHi0 + (w << 5) + lrow + ii * 8;
      er = er < SB ? er : SB - 1;
      int slot0 = ((w << 5) + ii * 8 + phHi0) & 127;
      gload_lds16(Eh + (size_t)er * DKB + cE * 8, Ehi_s + (slot0 << 6));
    }
    int rbLo0 = SB - 64 - qb0;
    int phLo0 = rbLo0 & 64;
#pragma unroll
    for (int ii = 0; ii < 4; ++ii) {
      int er = rbLo0 + (w << 5) + lrow + ii * 8;
      er = er < SB ? er : SB - 1;
      int slot0 = ((w << 5) + ii * 8 + phLo0) & 127;
      gload_lds16(Eh + (size_t)er * DKB + cE * 8, Elo_s + (slot0 << 6));
    }
  }
  __syncthreads();

  u32x4 rK0, rK1, rV0, rV1, rEh0, rEh1, rEl0, rEl1;

  for (int t = 0; t < ntrips; ++t) {
    int j0 = t << 6;
    int phHi = (SB - 64 - qb1 + j0) & 64;
    int phLo = (SB - 64 - qb0 + j0) & 64;
    bool pf = (t + 1 < ntrips);
    bool pfLo = (t + 1 <= g);
    // ---- issue prefetch loads for t+1 (pinned early by sched_barrier) ----
    if (pf) {
      int j0n = j0 + 64;
      rK0 = *(const u32x4*)(Kh + (size_t)(j0n + rKV) * DKB + cKV * 8);
      rK1 = *(const u32x4*)(Kh + (size_t)(j0n + rKV + 8) * DKB + cKV * 8);
      rV0 = *(const u32x4*)(Vh + (size_t)rKV * SB + j0n + cKV * 8);
      rV1 = *(const u32x4*)(Vh + (size_t)(rKV + 8) * SB + j0n + cKV * 8);
      int eb0 = SB - 64 - qb1 + j0 + 128 + (w << 4) + lrow;  // t+1 new half
      int e0 = eb0 < SB ? eb0 : SB - 1;
      int e1 = (eb0 + 8) < SB ? (eb0 + 8) : SB - 1;
      rEh0 = *(const u32x4*)(Eh + (size_t)e0 * DKB + cE * 8);
      rEh1 = *(const u32x4*)(Eh + (size_t)e1 * DKB + cE * 8);
      if (pfLo) {
        int fb0 = SB - 64 - qb0 + j0 + 128 + (w << 4) + lrow;
        int f0 = fb0 < SB ? fb0 : SB - 1;
        int f1 = (fb0 + 8) < SB ? (fb0 + 8) : SB - 1;
        rEl0 = *(const u32x4*)(Eh + (size_t)f0 * DKB + cE * 8);
        rEl1 = *(const u32x4*)(Eh + (size_t)f1 * DKB + cE * 8);
      }
    }
    __builtin_amdgcn_sched_barrier(0);  // pin load ISSUE above all compute
    // ---- compute trip t ----
    bool actLo = (t <= g);
    {
      bf16x8 kf[8];
#pragma unroll
      for (int hh = 0; hh < 4; ++hh) {
        int rk = hh * 16 + lr;
        const short* kb = Ks + rk * 64;
        kf[hh * 2] = *(const bf16x8*)(kb + ((lq ^ (rk & 7)) << 3));
        kf[hh * 2 + 1] = *(const bf16x8*)(kb + (((lq + 4) ^ (rk & 7)) << 3));
      }
      f32x4 scH[4], scL[4];
#pragma unroll
      for (int hh = 0; hh < 4; ++hh)
        scH[hh] = mfma16(kf[hh * 2 + 1], qh1, mfma16(kf[hh * 2], qh0, zz));
      if (actLo) {
#pragma unroll
        for (int hh = 0; hh < 4; ++hh)
          scL[hh] = mfma16(kf[hh * 2 + 1], ql1, mfma16(kf[hh * 2], ql0, zz));
      }
      bf16x8 vf[8];
#pragma unroll
      for (int kc = 0; kc < 2; ++kc)
#pragma unroll
        for (int dt = 0; dt < 4; ++dt) {
          int rv = dt * 16 + lr;
          vf[kc * 4 + dt] = *(const bf16x8*)(Vs + rv * 64 +
                                             (((kc * 4 + lq) ^ (rv & 7)) << 3));
        }
      e_phase_lds(Ehi_s, w, phHi, qh0, qh1, bdH, lr, lq);
      if (actLo) e_phase_lds(Elo_s, w, phLo, ql0, ql1, bdL, lr, lq);
      sm_step(scH, bdH, bdH, accH, mH, lsH, i0hi, j0, lr, lq);
      if (actLo) sm_step(scL, bdL, bdL, accL, mL, lsL, i0lo, j0, lr, lq);
      pv_step(bdH, vf, accH, lr, lq);
      if (actLo) pv_step(bdL, vf, accL, lr, lq);
    }
    // ---- write prefetched data between barriers ----
    if (pf) {
      __syncthreads();  // B: all reads of trip t done
      *(u32x4*)(Ks + (w << 10) + l * 8) = rK0;
      *(u32x4*)(Ks + (w << 10) + 512 + l * 8) = rK1;
      *(u32x4*)(Vs + (w << 10) + l * 8) = rV0;
      *(u32x4*)(Vs + (w << 10) + 512 + l * 8) = rV1;
      int s0 = ((w << 4) + phHi) & 127;        // slot of (row & 127) for t+1
      int s1 = ((w << 4) + 8 + phHi) & 127;
      *(u32x4*)(Ehi_s + (s0 << 6) + l * 8) = rEh0;
      *(u32x4*)(Ehi_s + (s1 << 6) + l * 8) = rEh1;
      if (pfLo) {
        int s2 = ((w << 4) + phLo) & 127;
        int s3 = ((w << 4) + 8 + phLo) & 127;
        *(u32x4*)(Elo_s + (s2 << 6) + l * 8) = rEl0;
        *(u32x4*)(Elo_s + (s3 << 6) + l * 8) = rEl1;
      }
      __syncthreads();  // A for trip t+1
    }
  }
  attn_out(accH, lsH, out, bh, i0hi, lr, lq);
  attn_out(accL, lsL, out, bh, i0lo, lr, lq);
}

// ---------------- host ----------------
extern "C" void kernel_launch(void* const* d_in, const int* in_sizes, int n_in,
                              void* d_out, int out_size, void* d_ws, size_t ws_size,
                              hipStream_t stream) {
  const float* x    = (const float*)d_in[0];
  const float* wq   = (const float*)d_in[2];
  const float* wk   = (const float*)d_in[3];
  const float* wv   = (const float*)d_in[4];
  const float* w0   = (const float*)d_in[5];
  const float* b0   = (const float*)d_in[6];
  const float* rel  = (const float*)d_in[7];
  const float* ln1g = (const float*)d_in[8];
  const float* ln1b = (const float*)d_in[9];
  const float* ln2g = (const float*)d_in[10];
  const float* ln2b = (const float*)d_in[11];
  const float* fw1  = (const float*)d_in[12];
  const float* fb1  = (const float*)d_in[13];
  const float* fw2  = (const float*)d_in[14];
  const float* fb2  = (const float*)d_in[15];
  float* outp = (float*)d_out;

  char* ws = (char*)d_ws;
  size_t off = 0;
  auto alloc = [&](size_t bytes) {
    char* p = ws + off;
    off += (bytes + 255) & ~(size_t)255;
    return p;
  };
  short* wqkvT = (short*)alloc((size_t)1536 * 512 * 2);  // contiguous with w0T
  short* w0T   = (short*)alloc((size_t)512 * 512 * 2);   // == wqkvT + 3*512*512
  short* fw1T  = (short*)alloc((size_t)2048 * 512 * 2);
  short* fw2T  = (short*)alloc((size_t)512 * 2048 * 2);
  short* relb  = (short*)alloc((size_t)8 * 2048 * 64 * 2);
  short* hbuf  = (short*)alloc((size_t)8192 * 512 * 2);
  short* Qb    = (short*)alloc((size_t)8192 * 512 * 2);
  short* Kbf   = (short*)alloc((size_t)8192 * 512 * 2);
  short* VTb   = (short*)alloc((size_t)8192 * 512 * 2);
  short* attnb = (short*)alloc((size_t)8192 * 512 * 2);
  float* x2    = (float*)alloc((size_t)8192 * 512 * 4);
  short* ff1 = hbuf;          // FF1 output aliases h (dead after QKV gemm)
  short* h2  = attnb;         // h2 aliases attn output (dead after O-proj)
  (void)w0T;

  dim3 blk(256);
  // merged prep: rel conv (4096) + 4x512^2 transpose (256) + fw1 (256) +
  // fw2 (256) + LN1 (2048) = 6912 blocks, one launch
  prep_kernel<<<6912, blk, 0, stream>>>(rel, relb, wq, wk, wv, w0, wqkvT,
                                        fw1, fw1T, fw2, fw2T,
                                        x, ln1g, ln1b, hbuf);
  gemm_kernel<512, 0><<<dim3(12, 64), blk, 0, stream>>>(hbuf, wqkvT, nullptr, nullptr,
                                                        Qb, Kbf, VTb, nullptr);
  attn_kernel<<<512, blk, 0, stream>>>(Qb, Kbf, VTb, relb, attnb);
  gemm64_kernel<512><<<dim3(8, 64), blk, 0, stream>>>(attnb, wqkvT + (size_t)3 * 512 * 512,
                                                      b0, x, x2);
  ln_kernel<<<2048, blk, 0, stream>>>(x2, ln2g, ln2b, h2);
  gemm_kernel<512, 2><<<dim3(16, 64), blk, 0, stream>>>(h2, fw1T, fb1, nullptr,
                                                        ff1, nullptr, nullptr, nullptr);
  gemm64_kernel<2048><<<dim3(8, 64), blk, 0, stream>>>(ff1, fw2T, fb2, x2, outp);
}

// Round 22
// 203.815 us; speedup vs baseline: 1.1054x; 1.0582x over previous
//
#include <hip/hip_runtime.h>
#include <hip/hip_bf16.h>

// Problem constants
#define SB 2048
#define DB 512
#define HB 8
#define DKB 64
#define DFB 2048
#define BATCH 4
#define BSTR 92   // band/P LDS row stride in shorts (184B: 14 dw mod 32, gcd 2)

typedef __attribute__((ext_vector_type(8))) short bf16x8;
typedef __attribute__((ext_vector_type(4))) float f32x4;
typedef __attribute__((ext_vector_type(2))) float f32x2;
typedef __attribute__((ext_vector_type(2))) unsigned u32x2;
typedef __attribute__((ext_vector_type(4))) unsigned u32x4;
typedef __attribute__((ext_vector_type(4))) short s16x4;

static __device__ __forceinline__ short f2bf(float x) {
  union { float f; unsigned u; } v; v.f = x;
  unsigned r = (v.u + 0x7fffu + ((v.u >> 16) & 1u)) >> 16;
  return (short)(unsigned short)r;
}

static __device__ __forceinline__ float bflo(unsigned u) {
  union { unsigned x; float f; } v; v.x = u << 16; return v.f;
}
static __device__ __forceinline__ float bfhi(unsigned u) {
  union { unsigned x; float f; } v; v.x = u & 0xffff0000u; return v.f;
}

static __device__ __forceinline__ unsigned pack2bf(float a, float b) {
  return (unsigned)(unsigned short)f2bf(a) | ((unsigned)(unsigned short)f2bf(b) << 16);
}

static __device__ __forceinline__ f32x4 mfma16(bf16x8 a, bf16x8 b, f32x4 c) {
  return __builtin_amdgcn_mfma_f32_16x16x32_bf16(a, b, c, 0, 0, 0);
}

// raw hardware 2^x (v_exp_f32); exp2f() is the precise libm path (R16 regr.)
static __device__ __forceinline__ float fexp2(float x) {
#if __has_builtin(__builtin_amdgcn_exp2f)
  return __builtin_amdgcn_exp2f(x);
#else
  float r;
  asm("v_exp_f32 %0, %1" : "=v"(r) : "v"(x));
  return r;
#endif
}

// async global->LDS, 16B per lane; LDS dest is wave-uniform base + lane*16
static __device__ __forceinline__ void gload_lds16(const short* g, short* l) {
  __builtin_amdgcn_global_load_lds(
      (const __attribute__((address_space(1))) unsigned*)g,
      (__attribute__((address_space(3))) unsigned*)l, 16, 0, 0);
}

// ---------------- merged prep: rel-conv + 4x weight transpose + fw1/fw2
// transpose + LN1, one launch (all input-only, mutually independent).
__global__ __launch_bounds__(256) void prep_kernel(
    const float* __restrict__ rel, short* __restrict__ relb,
    const float* __restrict__ wq, const float* __restrict__ wk,
    const float* __restrict__ wv, const float* __restrict__ w0,
    short* __restrict__ wqkvT,
    const float* __restrict__ fw1, short* __restrict__ fw1T,
    const float* __restrict__ fw2, short* __restrict__ fw2T,
    const float* __restrict__ x, const float* __restrict__ ln1g,
    const float* __restrict__ ln1b, short* __restrict__ hbuf) {
  __shared__ float t[64][65];
  int b = blockIdx.x;
  int tid = threadIdx.x;
  if (b < 4096) {
    int i = b * 256 + tid;
    relb[i] = f2bf(rel[i]);
  } else if (b < 4864) {
    const float* src;
    short* dst;
    int K, N, n0, k0;
    float scale = 1.f;
    if (b < 4352) {
      int idx = b - 4096;
      int z = idx >> 6;
      src = z == 0 ? wq : (z == 1 ? wk : (z == 2 ? wv : w0));
      scale = (z == 0) ? 1.4426950408889634f : ((z == 1) ? 0.125f : 1.f);
      dst = wqkvT + (size_t)z * 512 * 512;
      K = 512; N = 512;
      n0 = (idx & 7) * 64;
      k0 = ((idx >> 3) & 7) * 64;
    } else if (b < 4608) {
      int idx = b - 4352;
      src = fw1; dst = fw1T; K = 512; N = 2048;
      n0 = (idx & 31) * 64;
      k0 = (idx >> 5) * 64;
    } else {
      int idx = b - 4608;
      src = fw2; dst = fw2T; K = 2048; N = 512;
      n0 = (idx & 7) * 64;
      k0 = (idx >> 3) * 64;
    }
    int cn = tid & 63, rk = tid >> 6;
#pragma unroll
    for (int r = 0; r < 16; ++r)
      t[rk + r * 4][cn] = src[(size_t)(k0 + rk + r * 4) * N + n0 + cn];
    __syncthreads();
#pragma unroll
    for (int r = 0; r < 16; ++r)
      dst[(size_t)(n0 + rk + r * 4) * K + k0 + cn] = f2bf(t[cn][rk + r * 4] * scale);
  } else {
    int idx = b - 4864;
    int w = tid >> 6, l = tid & 63;
    size_t row = (size_t)idx * 4 + w;
    const float* xr = x + row * DB;
    f32x4 v0 = *(const f32x4*)(xr + l * 8);
    f32x4 v1 = *(const f32x4*)(xr + l * 8 + 4);
    float s = (v0[0] + v0[1]) + (v0[2] + v0[3]) + (v1[0] + v1[1]) + (v1[2] + v1[3]);
    float s2 = (v0[0] * v0[0] + v0[1] * v0[1]) + (v0[2] * v0[2] + v0[3] * v0[3]) +
               (v1[0] * v1[0] + v1[1] * v1[1]) + (v1[2] * v1[2] + v1[3] * v1[3]);
#pragma unroll
    for (int off = 1; off < 64; off <<= 1) {
      s += __shfl_xor(s, off, 64);
      s2 += __shfl_xor(s2, off, 64);
    }
    float mean = s * (1.f / DB);
    float var = s2 * (1.f / DB) - mean * mean;
    float rstd = rsqrtf(var + 1e-6f);
    f32x4 g0 = *(const f32x4*)(ln1g + l * 8);
    f32x4 g1 = *(const f32x4*)(ln1g + l * 8 + 4);
    f32x4 b0 = *(const f32x4*)(ln1b + l * 8);
    f32x4 b1 = *(const f32x4*)(ln1b + l * 8 + 4);
    bf16x8 ov;
#pragma unroll
    for (int e = 0; e < 4; ++e) ov[e] = f2bf((v0[e] - mean) * rstd * g0[e] + b0[e]);
#pragma unroll
    for (int e = 0; e < 4; ++e) ov[4 + e] = f2bf((v1[e] - mean) * rstd * g1[e] + b1[e]);
    *(bf16x8*)(hbuf + row * DB + l * 8) = ov;
  }
}

// ---------------- layernorm (LN2): one wave per 512-elem row --------------
__global__ __launch_bounds__(256) void ln_kernel(const float* __restrict__ in,
                                                 const float* __restrict__ g,
                                                 const float* __restrict__ bb,
                                                 short* __restrict__ out) {
  int w = threadIdx.x >> 6, l = threadIdx.x & 63;
  size_t row = (size_t)blockIdx.x * 4 + w;
  const float* xr = in + row * DB;
  f32x4 v0 = *(const f32x4*)(xr + l * 8);
  f32x4 v1 = *(const f32x4*)(xr + l * 8 + 4);
  float s = (v0[0] + v0[1]) + (v0[2] + v0[3]) + (v1[0] + v1[1]) + (v1[2] + v1[3]);
  float s2 = (v0[0] * v0[0] + v0[1] * v0[1]) + (v0[2] * v0[2] + v0[3] * v0[3]) +
             (v1[0] * v1[0] + v1[1] * v1[1]) + (v1[2] * v1[2] + v1[3] * v1[3]);
#pragma unroll
  for (int off = 1; off < 64; off <<= 1) {
    s += __shfl_xor(s, off, 64);
    s2 += __shfl_xor(s2, off, 64);
  }
  float mean = s * (1.f / DB);
  float var = s2 * (1.f / DB) - mean * mean;
  float rstd = rsqrtf(var + 1e-6f);
  f32x4 g0 = *(const f32x4*)(g + l * 8);
  f32x4 g1 = *(const f32x4*)(g + l * 8 + 4);
  f32x4 b0 = *(const f32x4*)(bb + l * 8);
  f32x4 b1 = *(const f32x4*)(bb + l * 8 + 4);
  bf16x8 ov;
#pragma unroll
  for (int e = 0; e < 4; ++e) ov[e] = f2bf((v0[e] - mean) * rstd * g0[e] + b0[e]);
#pragma unroll
  for (int e = 0; e < 4; ++e) ov[4 + e] = f2bf((v1[e] - mean) * rstd * g1[e] + b1[e]);
  *(bf16x8*)(out + row * DB + l * 8) = ov;
}

// ---------------- GEMM 128x128, BK=32 dbuf + 4-chunk swizzle + T1 XCD -----
// T1 bijective XCD swizzle: consecutive wid (sharing an A row-stripe) land
// on ONE XCD -> A panels become L2-resident instead of L3-refetched 8x.
template <int KD, int EPI>
__global__ __launch_bounds__(256) void gemm_kernel(
    const short* __restrict__ A, const short* __restrict__ BT,
    const float* __restrict__ bias, const float* __restrict__ resid,
    short* __restrict__ o0, short* __restrict__ o1, short* __restrict__ o2,
    float* __restrict__ of) {
  __shared__ short As[2][4096];  // 128 rows x 32 k
  __shared__ short Bs[2][4096];
  int tid = threadIdx.x;
  int l = tid & 63, w = tid >> 6;
  int wr = w >> 1, wc = w & 1;
  int lr = l & 15, lq = l >> 4;
  int nwgx = gridDim.x;
  int flat = blockIdx.y * nwgx + blockIdx.x;
  int nwg = nwgx * gridDim.y;                    // divisible by 8
  int wid = (flat & 7) * (nwg >> 3) + (flat >> 3);
  int row0 = (wid / nwgx) * 128;
  int col0 = (wid % nwgx) * 128;

  f32x4 acc[4][4];
#pragma unroll
  for (int a = 0; a < 4; ++a)
#pragma unroll
    for (int b = 0; b < 4; ++b) acc[a][b] = (f32x4){0.f, 0.f, 0.f, 0.f};

  int srow = tid >> 2;                   // [0,64); also stages srow+64
  int scol = (tid & 3) ^ (srow & 3);     // inverse-swizzled source chunk
  const short* gA = A + (size_t)(row0 + srow) * KD + scol * 8;
  const short* gB = BT + (size_t)(col0 + srow) * KD + scol * 8;
  const size_t step64 = (size_t)64 * KD;
  int woff = w * 512;

  auto stage = [&](int buf, int k0) {
    gload_lds16(gA + k0, As[buf] + woff);
    gload_lds16(gA + step64 + k0, As[buf] + woff + 2048);
    gload_lds16(gB + k0, Bs[buf] + woff);
    gload_lds16(gB + step64 + k0, Bs[buf] + woff + 2048);
  };

  stage(0, 0);
  __syncthreads();
  int cur = 0;
  for (int k0 = 0; k0 < KD; k0 += 32) {
    if (k0 + 32 < KD) stage(cur ^ 1, k0 + 32);  // prefetch next tile
    bf16x8 af[4], bfv[4];
#pragma unroll
    for (int a = 0; a < 4; ++a) {
      int rk = wr * 64 + a * 16 + lr;
      af[a] = *(const bf16x8*)(As[cur] + rk * 32 + ((lq ^ (rk & 3)) << 3));
    }
#pragma unroll
    for (int b = 0; b < 4; ++b) {
      int rk = wc * 64 + b * 16 + lr;
      bfv[b] = *(const bf16x8*)(Bs[cur] + rk * 32 + ((lq ^ (rk & 3)) << 3));
    }
#pragma unroll
    for (int a = 0; a < 4; ++a)
#pragma unroll
      for (int b = 0; b < 4; ++b)
        acc[a][b] = mfma16(af[a], bfv[b], acc[a][b]);
    __syncthreads();
    cur ^= 1;
  }

#pragma unroll
  for (int a = 0; a < 4; ++a)
#pragma unroll
    for (int b = 0; b < 4; ++b) {
      size_t colb = (size_t)col0 + wc * 64 + b * 16 + lr;
      if (EPI == 0 && (int)(colb >> 9) == 2) {
        int d = (int)(colb & 63);
        size_t rowb = (size_t)row0 + wr * 64 + a * 16 + lq * 4;
        size_t b_ = rowb >> 11, s_ = rowb & 2047;
        size_t bh = b_ * HB + (int)((colb >> 6) & 7);
        s16x4 pkv;
#pragma unroll
        for (int r = 0; r < 4; ++r) pkv[r] = f2bf(acc[a][b][r]);
        *(s16x4*)(o2 + (bh * DKB + d) * SB + s_) = pkv;
        continue;
      }
#pragma unroll
      for (int r = 0; r < 4; ++r) {
        size_t row = (size_t)row0 + wr * 64 + a * 16 + lq * 4 + r;
        size_t col = colb;
        float val = acc[a][b][r];
        if (EPI == 0) {
          int sect = (int)(col >> 9);
          int hh = (int)((col >> 6) & 7);
          int d = (int)(col & 63);
          size_t b_ = row >> 11, s_ = row & 2047;
          size_t bh = b_ * HB + hh;
          short bv = f2bf(val);
          if (sect == 0) o0[(bh * SB + s_) * DKB + d] = bv;
          else o1[(bh * SB + s_) * DKB + d] = bv;
        } else if (EPI == 1) {
          of[row * DB + col] = resid[row * DB + col] + val + bias[col];
        } else {
          float tv = val + bias[col];
          o0[row * DFB + col] = f2bf(tv > 0.f ? tv : 0.f);
        }
      }
    }
}

// ---------------- GEMM 128x64, BK=32 dbuf + swizzle + T1 XCD (O-proj/FF2) -
template <int KD>
__global__ __launch_bounds__(256) void gemm64_kernel(
    const short* __restrict__ A, const short* __restrict__ BT,
    const float* __restrict__ bias, const float* __restrict__ resid,
    float* __restrict__ of) {
  __shared__ short As[2][4096];  // 128 x 32
  __shared__ short Bs[2][2048];  // 64 x 32
  int tid = threadIdx.x;
  int l = tid & 63, w = tid >> 6;
  int lr = l & 15, lq = l >> 4;
  int nwgx = gridDim.x;
  int flat = blockIdx.y * nwgx + blockIdx.x;
  int nwg = nwgx * gridDim.y;                    // divisible by 8
  int wid = (flat & 7) * (nwg >> 3) + (flat >> 3);
  int row0 = (wid / nwgx) * 128;
  int col0 = (wid % nwgx) * 64;

  f32x4 acc[2][4];
#pragma unroll
  for (int a = 0; a < 2; ++a)
#pragma unroll
    for (int b = 0; b < 4; ++b) acc[a][b] = (f32x4){0.f, 0.f, 0.f, 0.f};

  int srow = tid >> 2;
  int scol = (tid & 3) ^ (srow & 3);
  const short* gA = A + (size_t)(row0 + srow) * KD + scol * 8;
  const short* gB = BT + (size_t)(col0 + srow) * KD + scol * 8;
  const size_t step64 = (size_t)64 * KD;
  int woff = w * 512;

  auto stage = [&](int buf, int k0) {
    gload_lds16(gA + k0, As[buf] + woff);
    gload_lds16(gA + step64 + k0, As[buf] + woff + 2048);
    gload_lds16(gB + k0, Bs[buf] + woff);
  };

  stage(0, 0);
  __syncthreads();
  int cur = 0;
  for (int k0 = 0; k0 < KD; k0 += 32) {
    if (k0 + 32 < KD) stage(cur ^ 1, k0 + 32);
    bf16x8 af[2], bfv[4];
#pragma unroll
    for (int a = 0; a < 2; ++a) {
      int rk = w * 32 + a * 16 + lr;
      af[a] = *(const bf16x8*)(As[cur] + rk * 32 + ((lq ^ (rk & 3)) << 3));
    }
#pragma unroll
    for (int b = 0; b < 4; ++b) {
      int rk = b * 16 + lr;
      bfv[b] = *(const bf16x8*)(Bs[cur] + rk * 32 + ((lq ^ (rk & 3)) << 3));
    }
#pragma unroll
    for (int a = 0; a < 2; ++a)
#pragma unroll
      for (int b = 0; b < 4; ++b)
        acc[a][b] = mfma16(af[a], bfv[b], acc[a][b]);
    __syncthreads();
    cur ^= 1;
  }

#pragma unroll
  for (int a = 0; a < 2; ++a)
#pragma unroll
    for (int b = 0; b < 4; ++b)
#pragma unroll
      for (int r = 0; r < 4; ++r) {
        size_t row = (size_t)row0 + w * 32 + a * 16 + lq * 4 + r;
        size_t col = (size_t)col0 + b * 16 + lr;
        of[row * DB + col] = resid[row * DB + col] + acc[a][b][r] + bias[col];
      }
}

// ---------------- attention helpers ----------------
static __device__ __forceinline__ void e_phase_lds(const short* Ebuf, int w, int ph,
                                                   bf16x8 q0, bf16x8 q1,
                                                   short* bdx, int lr, int lq) {
  bf16x8 ef[10];
#pragma unroll
  for (int nt = 0; nt < 5; ++nt) {
    int re = 48 - 16 * w + nt * 16 + lr;
    int sr = (re + ph) & 127;
    const short* eb = Ebuf + sr * 64;
    ef[nt * 2] = *(const bf16x8*)(eb + ((lq ^ (sr & 7)) << 3));
    ef[nt * 2 + 1] = *(const bf16x8*)(eb + (((lq + 4) ^ (sr & 7)) << 3));
  }
  const f32x4 zz = {0.f, 0.f, 0.f, 0.f};
#pragma unroll
  for (int nt = 0; nt < 5; ++nt) {
    f32x4 rr = mfma16(ef[nt * 2 + 1], q1, mfma16(ef[nt * 2], q0, zz));
    u32x2 pk = {pack2bf(rr[0], rr[1]), pack2bf(rr[2], rr[3])};
    *(u32x2*)((char*)bdx + lr * (BSTR * 2) + (nt * 16 + lq * 4) * 2) = pk;
  }
}

// Defer-max softmax (2^x via raw v_exp; Q carries log2e). Vector band gather.
static __device__ __forceinline__ void sm_step(const f32x4* sc, const short* bd,
                                               short* pb, f32x4* acc,
                                               float& mrun, float& lsum,
                                               int i0, int j0, int lr, int lq) {
  int bbase = lq * 4 + 15 - lr;
  int o = bbase & 3;
  unsigned shb = (unsigned)(o & 1) * 16;
  bool hi2 = (o >= 2);
  float bv[4][4];
#pragma unroll
  for (int hh = 0; hh < 4; ++hh) {
    int w0 = (hh * 16 + bbase) & ~3;
    const unsigned* p = (const unsigned*)(bd + lr * BSTR + w0);
    unsigned W0 = p[0], W1 = p[1], W2 = p[2], W3 = p[3];
    unsigned X0 = hi2 ? W1 : W0;
    unsigned X1 = hi2 ? W2 : W1;
    unsigned X2 = hi2 ? W3 : W2;
    unsigned out0 = (unsigned)((((unsigned long long)X1 << 32) | X0) >> shb);
    unsigned out1 = (unsigned)((((unsigned long long)X2 << 32) | X1) >> shb);
    bv[hh][0] = bflo(out0);
    bv[hh][1] = bfhi(out0);
    bv[hh][2] = bflo(out1);
    bv[hh][3] = bfhi(out1);
  }
  float s[4][4];
  if (j0 + 63 > i0) {
    int thr = i0 + lr - j0;
#pragma unroll
    for (int hh = 0; hh < 4; ++hh)
#pragma unroll
      for (int r = 0; r < 4; ++r) {
        int n = hh * 16 + lq * 4 + r;
        float v = sc[hh][r] + bv[hh][r];
        s[hh][r] = (n <= thr) ? v : -1e30f;
      }
  } else {
#pragma unroll
    for (int hh = 0; hh < 4; ++hh)
#pragma unroll
      for (int r = 0; r < 4; ++r) s[hh][r] = sc[hh][r] + bv[hh][r];
  }
  float m0 = fmaxf(fmaxf(s[0][0], s[0][1]), fmaxf(s[0][2], s[0][3]));
  float m1 = fmaxf(fmaxf(s[1][0], s[1][1]), fmaxf(s[1][2], s[1][3]));
  float m2 = fmaxf(fmaxf(s[2][0], s[2][1]), fmaxf(s[2][2], s[2][3]));
  float m3 = fmaxf(fmaxf(s[3][0], s[3][1]), fmaxf(s[3][2], s[3][3]));
  float tm = fmaxf(fmaxf(m0, m1), fmaxf(m2, m3));
  if (!__all(tm <= mrun + 8.f)) {
    float tr = fmaxf(tm, __shfl_xor(tm, 16, 64));
    tr = fmaxf(tr, __shfl_xor(tr, 32, 64));
    float mnew = fmaxf(mrun, tr);
    float corr = fexp2(mrun - mnew);
    mrun = mnew;
    lsum *= corr;
#pragma unroll
    for (int dt = 0; dt < 4; ++dt) acc[dt] *= corr;
  }
#pragma unroll
  for (int hh = 0; hh < 4; ++hh) {
    float p0 = fexp2(s[hh][0] - mrun);
    float p1 = fexp2(s[hh][1] - mrun);
    float p2 = fexp2(s[hh][2] - mrun);
    float p3 = fexp2(s[hh][3] - mrun);
    lsum += (p0 + p1) + (p2 + p3);
    u32x2 pk = {pack2bf(p0, p1), pack2bf(p2, p3)};
    int byteoff = lr * (BSTR * 2) + ((((hh << 1) | (lq >> 1)) ^ (lr & 7)) << 4) + ((lq & 1) << 3);
    *(u32x2*)((char*)pb + byteoff) = pk;
  }
}

static __device__ __forceinline__ void pv_step(const short* pb, const bf16x8* vf,
                                               f32x4* acc, int lr, int lq) {
#pragma unroll
  for (int kc = 0; kc < 2; ++kc) {
    bf16x8 pf = *(const bf16x8*)((const char*)pb + lr * (BSTR * 2) +
                                 ((((kc << 2) | lq) ^ (lr & 7)) << 4));
    __builtin_amdgcn_s_setprio(1);
#pragma unroll
    for (int dt = 0; dt < 4; ++dt)
      acc[dt] = mfma16(vf[kc * 4 + dt], pf, acc[dt]);
    __builtin_amdgcn_s_setprio(0);
  }
}

static __device__ __forceinline__ void attn_out(const f32x4* acc, float lsum,
                                                short* out, int bh, int i0,
                                                int lr, int lq) {
  float lt = lsum + __shfl_xor(lsum, 16, 64);
  lt += __shfl_xor(lt, 32, 64);
  float inv = 1.f / lt;
  int b_ = bh >> 3, hd = bh & 7;
  short* orow = out + ((size_t)(b_ * SB + i0 + lr) * DB + hd * 64);
#pragma unroll
  for (int dt = 0; dt < 4; ++dt) {
    s16x4 pkv;
#pragma unroll
    for (int r = 0; r < 4; ++r) pkv[r] = f2bf(acc[dt][r] * inv);
    *(s16x4*)(orow + dt * 16 + lq * 4) = pkv;
  }
}

// ---------------- fused causal attention with relative positions ----------
// R18/R20 structure: block-cooperative staging, E rings, T14 reg prefetch.
__global__ __launch_bounds__(256, 2) void attn_kernel(
    const short* __restrict__ Q, const short* __restrict__ Kb,
    const short* __restrict__ VT, const short* __restrict__ Eb,
    short* __restrict__ out) {
  __shared__ short Ks[4096];
  __shared__ short Vs[4096];
  __shared__ short Elo_s[8192];     // 128-row ring
  __shared__ short Ehi_s[8192];     // 128-row ring
  __shared__ short bandP[4][2][16][BSTR];
  int tid = threadIdx.x;
  int l = tid & 63, w = tid >> 6;
  int lr = l & 15, lq = l >> 4;
  int bid = blockIdx.x;                  // 512 blocks
  int s = bid >> 3;                      // [0,64)
  int bh = (bid & 7) * 4 + (s >> 4);     // 4 heads per XCD slot
  int g = s & 15;
  int qb0 = g << 6;
  int qb1 = (31 - g) << 6;
  int i0lo = qb0 + (w << 4);
  int i0hi = qb1 + (w << 4);
  const short* Qh = Q + (size_t)bh * SB * DKB;
  const short* Kh = Kb + (size_t)bh * SB * DKB;
  const short* Vh = VT + (size_t)bh * DKB * SB;
  const short* Eh = Eb + (size_t)(bh & 7) * SB * DKB;

  bf16x8 ql0 = *(const bf16x8*)(Qh + (size_t)(i0lo + lr) * DKB + lq * 8);
  bf16x8 ql1 = *(const bf16x8*)(Qh + (size_t)(i0lo + lr) * DKB + 32 + lq * 8);
  bf16x8 qh0 = *(const bf16x8*)(Qh + (size_t)(i0hi + lr) * DKB + lq * 8);
  bf16x8 qh1 = *(const bf16x8*)(Qh + (size_t)(i0hi + lr) * DKB + 32 + lq * 8);

  int lrow = l >> 3, lch = l & 7;
  int rKV = (w << 4) + lrow;
  int cKV = lch ^ (rKV & 7);
  int cE = lch ^ lrow;                   // E swizzle: slot&7 == lrow

  const f32x4 zz = {0.f, 0.f, 0.f, 0.f};
  f32x4 accL[4], accH[4];
#pragma unroll
  for (int dt = 0; dt < 4; ++dt) { accL[dt] = zz; accH[dt] = zz; }
  float mL = -1e30f, lsL = 0.f, mH = -1e30f, lsH = 0.f;
  short* bdL = &bandP[w][0][0][0];
  short* bdH = &bandP[w][1][0][0];

  int ntrips = (qb1 >> 6) + 1;

  // ---- prologue: stage trip 0 fully via global_load_lds ----
  {
    gload_lds16(Kh + (size_t)rKV * DKB + cKV * 8, Ks + (w << 10));
    gload_lds16(Kh + (size_t)(rKV + 8) * DKB + cKV * 8, Ks + (w << 10) + 512);
    gload_lds16(Vh + (size_t)rKV * SB + cKV * 8, Vs + (w << 10));
    gload_lds16(Vh + (size_t)(rKV + 8) * SB + cKV * 8, Vs + (w << 10) + 512);
    int rbHi0 = SB - 64 - qb1;
    int phHi0 = rbHi0 & 64;
#pragma unroll
    for (int ii = 0; ii < 4; ++ii) {
      int er = rbHi0 + (w << 5) + lrow + ii * 8;
      er = er < SB ? er : SB - 1;
      int slot0 = ((w << 5) + ii * 8 + phHi0) & 127;
      gload_lds16(Eh + (size_t)er * DKB + cE * 8, Ehi_s + (slot0 << 6));
    }
    int rbLo0 = SB - 64 - qb0;
    int phLo0 = rbLo0 & 64;
#pragma unroll
    for (int ii = 0; ii < 4; ++ii) {
      int er = rbLo0 + (w << 5) + lrow + ii * 8;
      er = er < SB ? er : SB - 1;
      int slot0 = ((w << 5) + ii * 8 + phLo0) & 127;
      gload_lds16(Eh + (size_t)er * DKB + cE * 8, Elo_s + (slot0 << 6));
    }
  }
  __syncthreads();

  u32x4 rK0, rK1, rV0, rV1, rEh0, rEh1, rEl0, rEl1;

  for (int t = 0; t < ntrips; ++t) {
    int j0 = t << 6;
    int phHi = (SB - 64 - qb1 + j0) & 64;
    int phLo = (SB - 64 - qb0 + j0) & 64;
    bool pf = (t + 1 < ntrips);
    bool pfLo = (t + 1 <= g);
    // ---- issue prefetch loads for t+1 (pinned early by sched_barrier) ----
    if (pf) {
      int j0n = j0 + 64;
      rK0 = *(const u32x4*)(Kh + (size_t)(j0n + rKV) * DKB + cKV * 8);
      rK1 = *(const u32x4*)(Kh + (size_t)(j0n + rKV + 8) * DKB + cKV * 8);
      rV0 = *(const u32x4*)(Vh + (size_t)rKV * SB + j0n + cKV * 8);
      rV1 = *(const u32x4*)(Vh + (size_t)(rKV + 8) * SB + j0n + cKV * 8);
      int eb0 = SB - 64 - qb1 + j0 + 128 + (w << 4) + lrow;  // t+1 new half
      int e0 = eb0 < SB ? eb0 : SB - 1;
      int e1 = (eb0 + 8) < SB ? (eb0 + 8) : SB - 1;
      rEh0 = *(const u32x4*)(Eh + (size_t)e0 * DKB + cE * 8);
      rEh1 = *(const u32x4*)(Eh + (size_t)e1 * DKB + cE * 8);
      if (pfLo) {
        int fb0 = SB - 64 - qb0 + j0 + 128 + (w << 4) + lrow;
        int f0 = fb0 < SB ? fb0 : SB - 1;
        int f1 = (fb0 + 8) < SB ? (fb0 + 8) : SB - 1;
        rEl0 = *(const u32x4*)(Eh + (size_t)f0 * DKB + cE * 8);
        rEl1 = *(const u32x4*)(Eh + (size_t)f1 * DKB + cE * 8);
      }
    }
    __builtin_amdgcn_sched_barrier(0);  // pin load ISSUE above all compute
    // ---- compute trip t ----
    bool actLo = (t <= g);
    {
      bf16x8 kf[8];
#pragma unroll
      for (int hh = 0; hh < 4; ++hh) {
        int rk = hh * 16 + lr;
        const short* kb = Ks + rk * 64;
        kf[hh * 2] = *(const bf16x8*)(kb + ((lq ^ (rk & 7)) << 3));
        kf[hh * 2 + 1] = *(const bf16x8*)(kb + (((lq + 4) ^ (rk & 7)) << 3));
      }
      f32x4 scH[4], scL[4];
#pragma unroll
      for (int hh = 0; hh < 4; ++hh)
        scH[hh] = mfma16(kf[hh * 2 + 1], qh1, mfma16(kf[hh * 2], qh0, zz));
      if (actLo) {
#pragma unroll
        for (int hh = 0; hh < 4; ++hh)
          scL[hh] = mfma16(kf[hh * 2 + 1], ql1, mfma16(kf[hh * 2], ql0, zz));
      }
      bf16x8 vf[8];
#pragma unroll
      for (int kc = 0; kc < 2; ++kc)
#pragma unroll
        for (int dt = 0; dt < 4; ++dt) {
          int rv = dt * 16 + lr;
          vf[kc * 4 + dt] = *(const bf16x8*)(Vs + rv * 64 +
                                             (((kc * 4 + lq) ^ (rv & 7)) << 3));
        }
      e_phase_lds(Ehi_s, w, phHi, qh0, qh1, bdH, lr, lq);
      if (actLo) e_phase_lds(Elo_s, w, phLo, ql0, ql1, bdL, lr, lq);
      sm_step(scH, bdH, bdH, accH, mH, lsH, i0hi, j0, lr, lq);
      if (actLo) sm_step(scL, bdL, bdL, accL, mL, lsL, i0lo, j0, lr, lq);
      pv_step(bdH, vf, accH, lr, lq);
      if (actLo) pv_step(bdL, vf, accL, lr, lq);
    }
    // ---- write prefetched data between barriers ----
    if (pf) {
      __syncthreads();  // B: all reads of trip t done
      *(u32x4*)(Ks + (w << 10) + l * 8) = rK0;
      *(u32x4*)(Ks + (w << 10) + 512 + l * 8) = rK1;
      *(u32x4*)(Vs + (w << 10) + l * 8) = rV0;
      *(u32x4*)(Vs + (w << 10) + 512 + l * 8) = rV1;
      int s0 = ((w << 4) + phHi) & 127;        // slot of (row & 127) for t+1
      int s1 = ((w << 4) + 8 + phHi) & 127;
      *(u32x4*)(Ehi_s + (s0 << 6) + l * 8) = rEh0;
      *(u32x4*)(Ehi_s + (s1 << 6) + l * 8) = rEh1;
      if (pfLo) {
        int s2 = ((w << 4) + phLo) & 127;
        int s3 = ((w << 4) + 8 + phLo) & 127;
        *(u32x4*)(Elo_s + (s2 << 6) + l * 8) = rEl0;
        *(u32x4*)(Elo_s + (s3 << 6) + l * 8) = rEl1;
      }
      __syncthreads();  // A for trip t+1
    }
  }
  attn_out(accH, lsH, out, bh, i0hi, lr, lq);
  attn_out(accL, lsL, out, bh, i0lo, lr, lq);
}

// ---------------- host ----------------
extern "C" void kernel_launch(void* const* d_in, const int* in_sizes, int n_in,
                              void* d_out, int out_size, void* d_ws, size_t ws_size,
                              hipStream_t stream) {
  const float* x    = (const float*)d_in[0];
  const float* wq   = (const float*)d_in[2];
  const float* wk   = (const float*)d_in[3];
  const float* wv   = (const float*)d_in[4];
  const float* w0   = (const float*)d_in[5];
  const float* b0   = (const float*)d_in[6];
  const float* rel  = (const float*)d_in[7];
  const float* ln1g = (const float*)d_in[8];
  const float* ln1b = (const float*)d_in[9];
  const float* ln2g = (const float*)d_in[10];
  const float* ln2b = (const float*)d_in[11];
  const float* fw1  = (const float*)d_in[12];
  const float* fb1  = (const float*)d_in[13];
  const float* fw2  = (const float*)d_in[14];
  const float* fb2  = (const float*)d_in[15];
  float* outp = (float*)d_out;

  char* ws = (char*)d_ws;
  size_t off = 0;
  auto alloc = [&](size_t bytes) {
    char* p = ws + off;
    off += (bytes + 255) & ~(size_t)255;
    return p;
  };
  short* wqkvT = (short*)alloc((size_t)1536 * 512 * 2);  // contiguous with w0T
  short* w0T   = (short*)alloc((size_t)512 * 512 * 2);   // == wqkvT + 3*512*512
  short* fw1T  = (short*)alloc((size_t)2048 * 512 * 2);
  short* fw2T  = (short*)alloc((size_t)512 * 2048 * 2);
  short* relb  = (short*)alloc((size_t)8 * 2048 * 64 * 2);
  short* hbuf  = (short*)alloc((size_t)8192 * 512 * 2);
  short* Qb    = (short*)alloc((size_t)8192 * 512 * 2);
  short* Kbf   = (short*)alloc((size_t)8192 * 512 * 2);
  short* VTb   = (short*)alloc((size_t)8192 * 512 * 2);
  short* attnb = (short*)alloc((size_t)8192 * 512 * 2);
  float* x2    = (float*)alloc((size_t)8192 * 512 * 4);
  short* ff1 = hbuf;          // FF1 output aliases h (dead after QKV gemm)
  short* h2  = attnb;         // h2 aliases attn output (dead after O-proj)
  (void)w0T;

  dim3 blk(256);
  // merged prep: rel conv (4096) + 4x512^2 transpose (256) + fw1 (256) +
  // fw2 (256) + LN1 (2048) = 6912 blocks, one launch
  prep_kernel<<<6912, blk, 0, stream>>>(rel, relb, wq, wk, wv, w0, wqkvT,
                                        fw1, fw1T, fw2, fw2T,
                                        x, ln1g, ln1b, hbuf);
  gemm_kernel<512, 0><<<dim3(12, 64), blk, 0, stream>>>(hbuf, wqkvT, nullptr, nullptr,
                                                        Qb, Kbf, VTb, nullptr);
  attn_kernel<<<512, blk, 0, stream>>>(Qb, Kbf, VTb, relb, attnb);
  gemm64_kernel<512><<<dim3(8, 64), blk, 0, stream>>>(attnb, wqkvT + (size_t)3 * 512 * 512,
                                                      b0, x, x2);
  ln_kernel<<<2048, blk, 0, stream>>>(x2, ln2g, ln2b, h2);
  gemm_kernel<512, 2><<<dim3(16, 64), blk, 0, stream>>>(h2, fw1T, fb1, nullptr,
                                                        ff1, nullptr, nullptr, nullptr);
  gemm64_kernel<2048><<<dim3(8, 64), blk, 0, stream>>>(ff1, fw2T, fb2, x2, outp);
}

// Round 23
// 202.775 us; speedup vs baseline: 1.1110x; 1.0051x over previous
//
#include <hip/hip_runtime.h>
#include <hip/hip_bf16.h>

// Problem constants
#define SB 2048
#define DB 512
#define HB 8
#define DKB 64
#define DFB 2048
#define BATCH 4
#define BSTR 92   // band/P LDS row stride in shorts (184B: 14 dw mod 32, gcd 2)

typedef __attribute__((ext_vector_type(8))) short bf16x8;
typedef __attribute__((ext_vector_type(4))) float f32x4;
typedef __attribute__((ext_vector_type(2))) float f32x2;
typedef __attribute__((ext_vector_type(2))) unsigned u32x2;
typedef __attribute__((ext_vector_type(4))) unsigned u32x4;
typedef __attribute__((ext_vector_type(4))) short s16x4;

static __device__ __forceinline__ short f2bf(float x) {
  union { float f; unsigned u; } v; v.f = x;
  unsigned r = (v.u + 0x7fffu + ((v.u >> 16) & 1u)) >> 16;
  return (short)(unsigned short)r;
}

static __device__ __forceinline__ float bflo(unsigned u) {
  union { unsigned x; float f; } v; v.x = u << 16; return v.f;
}
static __device__ __forceinline__ float bfhi(unsigned u) {
  union { unsigned x; float f; } v; v.x = u & 0xffff0000u; return v.f;
}

static __device__ __forceinline__ unsigned pack2bf(float a, float b) {
  return (unsigned)(unsigned short)f2bf(a) | ((unsigned)(unsigned short)f2bf(b) << 16);
}

static __device__ __forceinline__ f32x4 mfma16(bf16x8 a, bf16x8 b, f32x4 c) {
  return __builtin_amdgcn_mfma_f32_16x16x32_bf16(a, b, c, 0, 0, 0);
}

// raw hardware 2^x (v_exp_f32); exp2f() is the precise libm path (R16 regr.)
static __device__ __forceinline__ float fexp2(float x) {
#if __has_builtin(__builtin_amdgcn_exp2f)
  return __builtin_amdgcn_exp2f(x);
#else
  float r;
  asm("v_exp_f32 %0, %1" : "=v"(r) : "v"(x));
  return r;
#endif
}

// async global->LDS, 16B per lane; LDS dest is wave-uniform base + lane*16
static __device__ __forceinline__ void gload_lds16(const short* g, short* l) {
  __builtin_amdgcn_global_load_lds(
      (const __attribute__((address_space(1))) unsigned*)g,
      (__attribute__((address_space(3))) unsigned*)l, 16, 0, 0);
}

// ---------------- merged prep: rel-conv (float4-vectorized) + 4x weight
// transpose + fw1/fw2 transpose + LN1, one launch.
__global__ __launch_bounds__(256) void prep_kernel(
    const float* __restrict__ rel, short* __restrict__ relb,
    const float* __restrict__ wq, const float* __restrict__ wk,
    const float* __restrict__ wv, const float* __restrict__ w0,
    short* __restrict__ wqkvT,
    const float* __restrict__ fw1, short* __restrict__ fw1T,
    const float* __restrict__ fw2, short* __restrict__ fw2T,
    const float* __restrict__ x, const float* __restrict__ ln1g,
    const float* __restrict__ ln1b, short* __restrict__ hbuf) {
  __shared__ float t[64][65];
  int b = blockIdx.x;
  int tid = threadIdx.x;
  if (b < 1024) {
    // rel conv vectorized: 1048576 floats = 1024 blocks * 256 thr * 4 elems
    int i = (b * 256 + tid) * 4;
    f32x4 v = *(const f32x4*)(rel + i);
    s16x4 o;
#pragma unroll
    for (int e = 0; e < 4; ++e) o[e] = f2bf(v[e]);
    *(s16x4*)(relb + i) = o;
  } else if (b < 1792) {
    const float* src;
    short* dst;
    int K, N, n0, k0;
    float scale = 1.f;
    if (b < 1280) {  // wq/wk/wv/w0 (512x512), 64 blocks each
      int idx = b - 1024;
      int z = idx >> 6;
      src = z == 0 ? wq : (z == 1 ? wk : (z == 2 ? wv : w0));
      scale = (z == 0) ? 1.4426950408889634f : ((z == 1) ? 0.125f : 1.f);
      dst = wqkvT + (size_t)z * 512 * 512;
      K = 512; N = 512;
      n0 = (idx & 7) * 64;
      k0 = ((idx >> 3) & 7) * 64;
    } else if (b < 1536) {  // fw1: K=512, N=2048
      int idx = b - 1280;
      src = fw1; dst = fw1T; K = 512; N = 2048;
      n0 = (idx & 31) * 64;
      k0 = (idx >> 5) * 64;
    } else {                // fw2: K=2048, N=512
      int idx = b - 1536;
      src = fw2; dst = fw2T; K = 2048; N = 512;
      n0 = (idx & 7) * 64;
      k0 = (idx >> 3) * 64;
    }
    int cn = tid & 63, rk = tid >> 6;
#pragma unroll
    for (int r = 0; r < 16; ++r)
      t[rk + r * 4][cn] = src[(size_t)(k0 + rk + r * 4) * N + n0 + cn];
    __syncthreads();
#pragma unroll
    for (int r = 0; r < 16; ++r)
      dst[(size_t)(n0 + rk + r * 4) * K + k0 + cn] = f2bf(t[cn][rk + r * 4] * scale);
  } else {
    // LN1: one wave per 512-elem row, 2048 blocks
    int idx = b - 1792;
    int w = tid >> 6, l = tid & 63;
    size_t row = (size_t)idx * 4 + w;
    const float* xr = x + row * DB;
    f32x4 v0 = *(const f32x4*)(xr + l * 8);
    f32x4 v1 = *(const f32x4*)(xr + l * 8 + 4);
    float s = (v0[0] + v0[1]) + (v0[2] + v0[3]) + (v1[0] + v1[1]) + (v1[2] + v1[3]);
    float s2 = (v0[0] * v0[0] + v0[1] * v0[1]) + (v0[2] * v0[2] + v0[3] * v0[3]) +
               (v1[0] * v1[0] + v1[1] * v1[1]) + (v1[2] * v1[2] + v1[3] * v1[3]);
#pragma unroll
    for (int off = 1; off < 64; off <<= 1) {
      s += __shfl_xor(s, off, 64);
      s2 += __shfl_xor(s2, off, 64);
    }
    float mean = s * (1.f / DB);
    float var = s2 * (1.f / DB) - mean * mean;
    float rstd = rsqrtf(var + 1e-6f);
    f32x4 g0 = *(const f32x4*)(ln1g + l * 8);
    f32x4 g1 = *(const f32x4*)(ln1g + l * 8 + 4);
    f32x4 b0 = *(const f32x4*)(ln1b + l * 8);
    f32x4 b1 = *(const f32x4*)(ln1b + l * 8 + 4);
    bf16x8 ov;
#pragma unroll
    for (int e = 0; e < 4; ++e) ov[e] = f2bf((v0[e] - mean) * rstd * g0[e] + b0[e]);
#pragma unroll
    for (int e = 0; e < 4; ++e) ov[4 + e] = f2bf((v1[e] - mean) * rstd * g1[e] + b1[e]);
    *(bf16x8*)(hbuf + row * DB + l * 8) = ov;
  }
}

// ---------------- layernorm (LN2): one wave per 512-elem row --------------
__global__ __launch_bounds__(256) void ln_kernel(const float* __restrict__ in,
                                                 const float* __restrict__ g,
                                                 const float* __restrict__ bb,
                                                 short* __restrict__ out) {
  int w = threadIdx.x >> 6, l = threadIdx.x & 63;
  size_t row = (size_t)blockIdx.x * 4 + w;
  const float* xr = in + row * DB;
  f32x4 v0 = *(const f32x4*)(xr + l * 8);
  f32x4 v1 = *(const f32x4*)(xr + l * 8 + 4);
  float s = (v0[0] + v0[1]) + (v0[2] + v0[3]) + (v1[0] + v1[1]) + (v1[2] + v1[3]);
  float s2 = (v0[0] * v0[0] + v0[1] * v0[1]) + (v0[2] * v0[2] + v0[3] * v0[3]) +
             (v1[0] * v1[1] * 0.f + v1[0] * v1[0] + v1[1] * v1[1]) + (v1[2] * v1[2] + v1[3] * v1[3]);
#pragma unroll
  for (int off = 1; off < 64; off <<= 1) {
    s += __shfl_xor(s, off, 64);
    s2 += __shfl_xor(s2, off, 64);
  }
  float mean = s * (1.f / DB);
  float var = s2 * (1.f / DB) - mean * mean;
  float rstd = rsqrtf(var + 1e-6f);
  f32x4 g0 = *(const f32x4*)(g + l * 8);
  f32x4 g1 = *(const f32x4*)(g + l * 8 + 4);
  f32x4 b0 = *(const f32x4*)(bb + l * 8);
  f32x4 b1 = *(const f32x4*)(bb + l * 8 + 4);
  bf16x8 ov;
#pragma unroll
  for (int e = 0; e < 4; ++e) ov[e] = f2bf((v0[e] - mean) * rstd * g0[e] + b0[e]);
#pragma unroll
  for (int e = 0; e < 4; ++e) ov[4 + e] = f2bf((v1[e] - mean) * rstd * g1[e] + b1[e]);
  *(bf16x8*)(out + row * DB + l * 8) = ov;
}

// ---------------- GEMM 128x128, BK=32 dbuf + 4-chunk swizzle + T1 XCD -----
template <int KD, int EPI>
__global__ __launch_bounds__(256) void gemm_kernel(
    const short* __restrict__ A, const short* __restrict__ BT,
    const float* __restrict__ bias, const float* __restrict__ resid,
    short* __restrict__ o0, short* __restrict__ o1, short* __restrict__ o2,
    float* __restrict__ of) {
  __shared__ short As[2][4096];  // 128 rows x 32 k
  __shared__ short Bs[2][4096];
  int tid = threadIdx.x;
  int l = tid & 63, w = tid >> 6;
  int wr = w >> 1, wc = w & 1;
  int lr = l & 15, lq = l >> 4;
  int nwgx = gridDim.x;
  int flat = blockIdx.y * nwgx + blockIdx.x;
  int nwg = nwgx * gridDim.y;                    // divisible by 8
  int wid = (flat & 7) * (nwg >> 3) + (flat >> 3);
  int row0 = (wid / nwgx) * 128;
  int col0 = (wid % nwgx) * 128;

  f32x4 acc[4][4];
#pragma unroll
  for (int a = 0; a < 4; ++a)
#pragma unroll
    for (int b = 0; b < 4; ++b) acc[a][b] = (f32x4){0.f, 0.f, 0.f, 0.f};

  int srow = tid >> 2;                   // [0,64); also stages srow+64
  int scol = (tid & 3) ^ (srow & 3);     // inverse-swizzled source chunk
  const short* gA = A + (size_t)(row0 + srow) * KD + scol * 8;
  const short* gB = BT + (size_t)(col0 + srow) * KD + scol * 8;
  const size_t step64 = (size_t)64 * KD;
  int woff = w * 512;

  auto stage = [&](int buf, int k0) {
    gload_lds16(gA + k0, As[buf] + woff);
    gload_lds16(gA + step64 + k0, As[buf] + woff + 2048);
    gload_lds16(gB + k0, Bs[buf] + woff);
    gload_lds16(gB + step64 + k0, Bs[buf] + woff + 2048);
  };

  stage(0, 0);
  __syncthreads();
  int cur = 0;
  for (int k0 = 0; k0 < KD; k0 += 32) {
    if (k0 + 32 < KD) stage(cur ^ 1, k0 + 32);  // prefetch next tile
    bf16x8 af[4], bfv[4];
#pragma unroll
    for (int a = 0; a < 4; ++a) {
      int rk = wr * 64 + a * 16 + lr;
      af[a] = *(const bf16x8*)(As[cur] + rk * 32 + ((lq ^ (rk & 3)) << 3));
    }
#pragma unroll
    for (int b = 0; b < 4; ++b) {
      int rk = wc * 64 + b * 16 + lr;
      bfv[b] = *(const bf16x8*)(Bs[cur] + rk * 32 + ((lq ^ (rk & 3)) << 3));
    }
#pragma unroll
    for (int a = 0; a < 4; ++a)
#pragma unroll
      for (int b = 0; b < 4; ++b)
        acc[a][b] = mfma16(af[a], bfv[b], acc[a][b]);
    __syncthreads();
    cur ^= 1;
  }

#pragma unroll
  for (int a = 0; a < 4; ++a)
#pragma unroll
    for (int b = 0; b < 4; ++b) {
      size_t colb = (size_t)col0 + wc * 64 + b * 16 + lr;
      if (EPI == 0 && (int)(colb >> 9) == 2) {
        int d = (int)(colb & 63);
        size_t rowb = (size_t)row0 + wr * 64 + a * 16 + lq * 4;
        size_t b_ = rowb >> 11, s_ = rowb & 2047;
        size_t bh = b_ * HB + (int)((colb >> 6) & 7);
        s16x4 pkv;
#pragma unroll
        for (int r = 0; r < 4; ++r) pkv[r] = f2bf(acc[a][b][r]);
        *(s16x4*)(o2 + (bh * DKB + d) * SB + s_) = pkv;
        continue;
      }
#pragma unroll
      for (int r = 0; r < 4; ++r) {
        size_t row = (size_t)row0 + wr * 64 + a * 16 + lq * 4 + r;
        size_t col = colb;
        float val = acc[a][b][r];
        if (EPI == 0) {
          int sect = (int)(col >> 9);
          int hh = (int)((col >> 6) & 7);
          int d = (int)(col & 63);
          size_t b_ = row >> 11, s_ = row & 2047;
          size_t bh = b_ * HB + hh;
          short bv = f2bf(val);
          if (sect == 0) o0[(bh * SB + s_) * DKB + d] = bv;
          else o1[(bh * SB + s_) * DKB + d] = bv;
        } else if (EPI == 1) {
          of[row * DB + col] = resid[row * DB + col] + val + bias[col];
        } else {
          float tv = val + bias[col];
          o0[row * DFB + col] = f2bf(tv > 0.f ? tv : 0.f);
        }
      }
    }
}

// ---------------- GEMM 128x64, BK=32 dbuf + swizzle + T1 XCD (O-proj/FF2) -
template <int KD>
__global__ __launch_bounds__(256) void gemm64_kernel(
    const short* __restrict__ A, const short* __restrict__ BT,
    const float* __restrict__ bias, const float* __restrict__ resid,
    float* __restrict__ of) {
  __shared__ short As[2][4096];  // 128 x 32
  __shared__ short Bs[2][2048];  // 64 x 32
  int tid = threadIdx.x;
  int l = tid & 63, w = tid >> 6;
  int lr = l & 15, lq = l >> 4;
  int nwgx = gridDim.x;
  int flat = blockIdx.y * nwgx + blockIdx.x;
  int nwg = nwgx * gridDim.y;                    // divisible by 8
  int wid = (flat & 7) * (nwg >> 3) + (flat >> 3);
  int row0 = (wid / nwgx) * 128;
  int col0 = (wid % nwgx) * 64;

  f32x4 acc[2][4];
#pragma unroll
  for (int a = 0; a < 2; ++a)
#pragma unroll
    for (int b = 0; b < 4; ++b) acc[a][b] = (f32x4){0.f, 0.f, 0.f, 0.f};

  int srow = tid >> 2;
  int scol = (tid & 3) ^ (srow & 3);
  const short* gA = A + (size_t)(row0 + srow) * KD + scol * 8;
  const short* gB = BT + (size_t)(col0 + srow) * KD + scol * 8;
  const size_t step64 = (size_t)64 * KD;
  int woff = w * 512;

  auto stage = [&](int buf, int k0) {
    gload_lds16(gA + k0, As[buf] + woff);
    gload_lds16(gA + step64 + k0, As[buf] + woff + 2048);
    gload_lds16(gB + k0, Bs[buf] + woff);
  };

  stage(0, 0);
  __syncthreads();
  int cur = 0;
  for (int k0 = 0; k0 < KD; k0 += 32) {
    if (k0 + 32 < KD) stage(cur ^ 1, k0 + 32);
    bf16x8 af[2], bfv[4];
#pragma unroll
    for (int a = 0; a < 2; ++a) {
      int rk = w * 32 + a * 16 + lr;
      af[a] = *(const bf16x8*)(As[cur] + rk * 32 + ((lq ^ (rk & 3)) << 3));
    }
#pragma unroll
    for (int b = 0; b < 4; ++b) {
      int rk = b * 16 + lr;
      bfv[b] = *(const bf16x8*)(Bs[cur] + rk * 32 + ((lq ^ (rk & 3)) << 3));
    }
#pragma unroll
    for (int a = 0; a < 2; ++a)
#pragma unroll
      for (int b = 0; b < 4; ++b)
        acc[a][b] = mfma16(af[a], bfv[b], acc[a][b]);
    __syncthreads();
    cur ^= 1;
  }

#pragma unroll
  for (int a = 0; a < 2; ++a)
#pragma unroll
    for (int b = 0; b < 4; ++b)
#pragma unroll
      for (int r = 0; r < 4; ++r) {
        size_t row = (size_t)row0 + w * 32 + a * 16 + lq * 4 + r;
        size_t col = (size_t)col0 + b * 16 + lr;
        of[row * DB + col] = resid[row * DB + col] + acc[a][b][r] + bias[col];
      }
}

// ---------------- attention helpers ----------------
static __device__ __forceinline__ void e_phase_lds(const short* Ebuf, int w, int ph,
                                                   bf16x8 q0, bf16x8 q1,
                                                   short* bdx, int lr, int lq) {
  bf16x8 ef[10];
#pragma unroll
  for (int nt = 0; nt < 5; ++nt) {
    int re = 48 - 16 * w + nt * 16 + lr;
    int sr = (re + ph) & 127;
    const short* eb = Ebuf + sr * 64;
    ef[nt * 2] = *(const bf16x8*)(eb + ((lq ^ (sr & 7)) << 3));
    ef[nt * 2 + 1] = *(const bf16x8*)(eb + (((lq + 4) ^ (sr & 7)) << 3));
  }
  const f32x4 zz = {0.f, 0.f, 0.f, 0.f};
#pragma unroll
  for (int nt = 0; nt < 5; ++nt) {
    f32x4 rr = mfma16(ef[nt * 2 + 1], q1, mfma16(ef[nt * 2], q0, zz));
    u32x2 pk = {pack2bf(rr[0], rr[1]), pack2bf(rr[2], rr[3])};
    *(u32x2*)((char*)bdx + lr * (BSTR * 2) + (nt * 16 + lq * 4) * 2) = pk;
  }
}

// Defer-max softmax (2^x via raw v_exp; Q carries log2e). Vector band gather.
static __device__ __forceinline__ void sm_step(const f32x4* sc, const short* bd,
                                               short* pb, f32x4* acc,
                                               float& mrun, float& lsum,
                                               int i0, int j0, int lr, int lq) {
  int bbase = lq * 4 + 15 - lr;
  int o = bbase & 3;
  unsigned shb = (unsigned)(o & 1) * 16;
  bool hi2 = (o >= 2);
  float bv[4][4];
#pragma unroll
  for (int hh = 0; hh < 4; ++hh) {
    int w0 = (hh * 16 + bbase) & ~3;
    const unsigned* p = (const unsigned*)(bd + lr * BSTR + w0);
    unsigned W0 = p[0], W1 = p[1], W2 = p[2], W3 = p[3];
    unsigned X0 = hi2 ? W1 : W0;
    unsigned X1 = hi2 ? W2 : W1;
    unsigned X2 = hi2 ? W3 : W2;
    unsigned out0 = (unsigned)((((unsigned long long)X1 << 32) | X0) >> shb);
    unsigned out1 = (unsigned)((((unsigned long long)X2 << 32) | X1) >> shb);
    bv[hh][0] = bflo(out0);
    bv[hh][1] = bfhi(out0);
    bv[hh][2] = bflo(out1);
    bv[hh][3] = bfhi(out1);
  }
  float s[4][4];
  if (j0 + 63 > i0) {
    int thr = i0 + lr - j0;
#pragma unroll
    for (int hh = 0; hh < 4; ++hh)
#pragma unroll
      for (int r = 0; r < 4; ++r) {
        int n = hh * 16 + lq * 4 + r;
        float v = sc[hh][r] + bv[hh][r];
        s[hh][r] = (n <= thr) ? v : -1e30f;
      }
  } else {
#pragma unroll
    for (int hh = 0; hh < 4; ++hh)
#pragma unroll
      for (int r = 0; r < 4; ++r) s[hh][r] = sc[hh][r] + bv[hh][r];
  }
  float m0 = fmaxf(fmaxf(s[0][0], s[0][1]), fmaxf(s[0][2], s[0][3]));
  float m1 = fmaxf(fmaxf(s[1][0], s[1][1]), fmaxf(s[1][2], s[1][3]));
  float m2 = fmaxf(fmaxf(s[2][0], s[2][1]), fmaxf(s[2][2], s[2][3]));
  float m3 = fmaxf(fmaxf(s[3][0], s[3][1]), fmaxf(s[3][2], s[3][3]));
  float tm = fmaxf(fmaxf(m0, m1), fmaxf(m2, m3));
  if (!__all(tm <= mrun + 8.f)) {
    float tr = fmaxf(tm, __shfl_xor(tm, 16, 64));
    tr = fmaxf(tr, __shfl_xor(tr, 32, 64));
    float mnew = fmaxf(mrun, tr);
    float corr = fexp2(mrun - mnew);
    mrun = mnew;
    lsum *= corr;
#pragma unroll
    for (int dt = 0; dt < 4; ++dt) acc[dt] *= corr;
  }
#pragma unroll
  for (int hh = 0; hh < 4; ++hh) {
    float p0 = fexp2(s[hh][0] - mrun);
    float p1 = fexp2(s[hh][1] - mrun);
    float p2 = fexp2(s[hh][2] - mrun);
    float p3 = fexp2(s[hh][3] - mrun);
    lsum += (p0 + p1) + (p2 + p3);
    u32x2 pk = {pack2bf(p0, p1), pack2bf(p2, p3)};
    int byteoff = lr * (BSTR * 2) + ((((hh << 1) | (lq >> 1)) ^ (lr & 7)) << 4) + ((lq & 1) << 3);
    *(u32x2*)((char*)pb + byteoff) = pk;
  }
}

static __device__ __forceinline__ void pv_step(const short* pb, const bf16x8* vf,
                                               f32x4* acc, int lr, int lq) {
#pragma unroll
  for (int kc = 0; kc < 2; ++kc) {
    bf16x8 pf = *(const bf16x8*)((const char*)pb + lr * (BSTR * 2) +
                                 ((((kc << 2) | lq) ^ (lr & 7)) << 4));
    __builtin_amdgcn_s_setprio(1);
#pragma unroll
    for (int dt = 0; dt < 4; ++dt)
      acc[dt] = mfma16(vf[kc * 4 + dt], pf, acc[dt]);
    __builtin_amdgcn_s_setprio(0);
  }
}

static __device__ __forceinline__ void attn_out(const f32x4* acc, float lsum,
                                                short* out, int bh, int i0,
                                                int lr, int lq) {
  float lt = lsum + __shfl_xor(lsum, 16, 64);
  lt += __shfl_xor(lt, 32, 64);
  float inv = 1.f / lt;
  int b_ = bh >> 3, hd = bh & 7;
  short* orow = out + ((size_t)(b_ * SB + i0 + lr) * DB + hd * 64);
#pragma unroll
  for (int dt = 0; dt < 4; ++dt) {
    s16x4 pkv;
#pragma unroll
    for (int r = 0; r < 4; ++r) pkv[r] = f2bf(acc[dt][r] * inv);
    *(s16x4*)(orow + dt * 16 + lq * 4) = pkv;
  }
}

// ---------------- fused causal attention with relative positions ----------
// R18/R20 structure: block-cooperative staging, E rings, T14 reg prefetch.
__global__ __launch_bounds__(256, 2) void attn_kernel(
    const short* __restrict__ Q, const short* __restrict__ Kb,
    const short* __restrict__ VT, const short* __restrict__ Eb,
    short* __restrict__ out) {
  __shared__ short Ks[4096];
  __shared__ short Vs[4096];
  __shared__ short Elo_s[8192];     // 128-row ring
  __shared__ short Ehi_s[8192];     // 128-row ring
  __shared__ short bandP[4][2][16][BSTR];
  int tid = threadIdx.x;
  int l = tid & 63, w = tid >> 6;
  int lr = l & 15, lq = l >> 4;
  int bid = blockIdx.x;                  // 512 blocks
  int s = bid >> 3;                      // [0,64)
  int bh = (bid & 7) * 4 + (s >> 4);     // 4 heads per XCD slot
  int g = s & 15;
  int qb0 = g << 6;
  int qb1 = (31 - g) << 6;
  int i0lo = qb0 + (w << 4);
  int i0hi = qb1 + (w << 4);
  const short* Qh = Q + (size_t)bh * SB * DKB;
  const short* Kh = Kb + (size_t)bh * SB * DKB;
  const short* Vh = VT + (size_t)bh * DKB * SB;
  const short* Eh = Eb + (size_t)(bh & 7) * SB * DKB;

  bf16x8 ql0 = *(const bf16x8*)(Qh + (size_t)(i0lo + lr) * DKB + lq * 8);
  bf16x8 ql1 = *(const bf16x8*)(Qh + (size_t)(i0lo + lr) * DKB + 32 + lq * 8);
  bf16x8 qh0 = *(const bf16x8*)(Qh + (size_t)(i0hi + lr) * DKB + lq * 8);
  bf16x8 qh1 = *(const bf16x8*)(Qh + (size_t)(i0hi + lr) * DKB + 32 + lq * 8);

  int lrow = l >> 3, lch = l & 7;
  int rKV = (w << 4) + lrow;
  int cKV = lch ^ (rKV & 7);
  int cE = lch ^ lrow;                   // E swizzle: slot&7 == lrow

  const f32x4 zz = {0.f, 0.f, 0.f, 0.f};
  f32x4 accL[4], accH[4];
#pragma unroll
  for (int dt = 0; dt < 4; ++dt) { accL[dt] = zz; accH[dt] = zz; }
  float mL = -1e30f, lsL = 0.f, mH = -1e30f, lsH = 0.f;
  short* bdL = &bandP[w][0][0][0];
  short* bdH = &bandP[w][1][0][0];

  int ntrips = (qb1 >> 6) + 1;

  // ---- prologue: stage trip 0 fully via global_load_lds ----
  {
    gload_lds16(Kh + (size_t)rKV * DKB + cKV * 8, Ks + (w << 10));
    gload_lds16(Kh + (size_t)(rKV + 8) * DKB + cKV * 8, Ks + (w << 10) + 512);
    gload_lds16(Vh + (size_t)rKV * SB + cKV * 8, Vs + (w << 10));
    gload_lds16(Vh + (size_t)(rKV + 8) * SB + cKV * 8, Vs + (w << 10) + 512);
    int rbHi0 = SB - 64 - qb1;
    int phHi0 = rbHi0 & 64;
#pragma unroll
    for (int ii = 0; ii < 4; ++ii) {
      int er = rbHi0 + (w << 5) + lrow + ii * 8;
      er = er < SB ? er : SB - 1;
      int slot0 = ((w << 5) + ii * 8 + phHi0) & 127;
      gload_lds16(Eh + (size_t)er * DKB + cE * 8, Ehi_s + (slot0 << 6));
    }
    int rbLo0 = SB - 64 - qb0;
    int phLo0 = rbLo0 & 64;
#pragma unroll
    for (int ii = 0; ii < 4; ++ii) {
      int er = rbLo0 + (w << 5) + lrow + ii * 8;
      er = er < SB ? er : SB - 1;
      int slot0 = ((w << 5) + ii * 8 + phLo0) & 127;
      gload_lds16(Eh + (size_t)er * DKB + cE * 8, Elo_s + (slot0 << 6));
    }
  }
  __syncthreads();

  u32x4 rK0, rK1, rV0, rV1, rEh0, rEh1, rEl0, rEl1;

  for (int t = 0; t < ntrips; ++t) {
    int j0 = t << 6;
    int phHi = (SB - 64 - qb1 + j0) & 64;
    int phLo = (SB - 64 - qb0 + j0) & 64;
    bool pf = (t + 1 < ntrips);
    bool pfLo = (t + 1 <= g);
    // ---- issue prefetch loads for t+1 (pinned early by sched_barrier) ----
    if (pf) {
      int j0n = j0 + 64;
      rK0 = *(const u32x4*)(Kh + (size_t)(j0n + rKV) * DKB + cKV * 8);
      rK1 = *(const u32x4*)(Kh + (size_t)(j0n + rKV + 8) * DKB + cKV * 8);
      rV0 = *(const u32x4*)(Vh + (size_t)rKV * SB + j0n + cKV * 8);
      rV1 = *(const u32x4*)(Vh + (size_t)(rKV + 8) * SB + j0n + cKV * 8);
      int eb0 = SB - 64 - qb1 + j0 + 128 + (w << 4) + lrow;  // t+1 new half
      int e0 = eb0 < SB ? eb0 : SB - 1;
      int e1 = (eb0 + 8) < SB ? (eb0 + 8) : SB - 1;
      rEh0 = *(const u32x4*)(Eh + (size_t)e0 * DKB + cE * 8);
      rEh1 = *(const u32x4*)(Eh + (size_t)e1 * DKB + cE * 8);
      if (pfLo) {
        int fb0 = SB - 64 - qb0 + j0 + 128 + (w << 4) + lrow;
        int f0 = fb0 < SB ? fb0 : SB - 1;
        int f1 = (fb0 + 8) < SB ? (fb0 + 8) : SB - 1;
        rEl0 = *(const u32x4*)(Eh + (size_t)f0 * DKB + cE * 8);
        rEl1 = *(const u32x4*)(Eh + (size_t)f1 * DKB + cE * 8);
      }
    }
    __builtin_amdgcn_sched_barrier(0);  // pin load ISSUE above all compute
    // ---- compute trip t ----
    bool actLo = (t <= g);
    {
      bf16x8 kf[8];
#pragma unroll
      for (int hh = 0; hh < 4; ++hh) {
        int rk = hh * 16 + lr;
        const short* kb = Ks + rk * 64;
        kf[hh * 2] = *(const bf16x8*)(kb + ((lq ^ (rk & 7)) << 3));
        kf[hh * 2 + 1] = *(const bf16x8*)(kb + (((lq + 4) ^ (rk & 7)) << 3));
      }
      f32x4 scH[4], scL[4];
#pragma unroll
      for (int hh = 0; hh < 4; ++hh)
        scH[hh] = mfma16(kf[hh * 2 + 1], qh1, mfma16(kf[hh * 2], qh0, zz));
      if (actLo) {
#pragma unroll
        for (int hh = 0; hh < 4; ++hh)
          scL[hh] = mfma16(kf[hh * 2 + 1], ql1, mfma16(kf[hh * 2], ql0, zz));
      }
      bf16x8 vf[8];
#pragma unroll
      for (int kc = 0; kc < 2; ++kc)
#pragma unroll
        for (int dt = 0; dt < 4; ++dt) {
          int rv = dt * 16 + lr;
          vf[kc * 4 + dt] = *(const bf16x8*)(Vs + rv * 64 +
                                             (((kc * 4 + lq) ^ (rv & 7)) << 3));
        }
      e_phase_lds(Ehi_s, w, phHi, qh0, qh1, bdH, lr, lq);
      if (actLo) e_phase_lds(Elo_s, w, phLo, ql0, ql1, bdL, lr, lq);
      sm_step(scH, bdH, bdH, accH, mH, lsH, i0hi, j0, lr, lq);
      if (actLo) sm_step(scL, bdL, bdL, accL, mL, lsL, i0lo, j0, lr, lq);
      pv_step(bdH, vf, accH, lr, lq);
      if (actLo) pv_step(bdL, vf, accL, lr, lq);
    }
    // ---- write prefetched data between barriers ----
    if (pf) {
      __syncthreads();  // B: all reads of trip t done
      *(u32x4*)(Ks + (w << 10) + l * 8) = rK0;
      *(u32x4*)(Ks + (w << 10) + 512 + l * 8) = rK1;
      *(u32x4*)(Vs + (w << 10) + l * 8) = rV0;
      *(u32x4*)(Vs + (w << 10) + 512 + l * 8) = rV1;
      int s0 = ((w << 4) + phHi) & 127;        // slot of (row & 127) for t+1
      int s1 = ((w << 4) + 8 + phHi) & 127;
      *(u32x4*)(Ehi_s + (s0 << 6) + l * 8) = rEh0;
      *(u32x4*)(Ehi_s + (s1 << 6) + l * 8) = rEh1;
      if (pfLo) {
        int s2 = ((w << 4) + phLo) & 127;
        int s3 = ((w << 4) + 8 + phLo) & 127;
        *(u32x4*)(Elo_s + (s2 << 6) + l * 8) = rEl0;
        *(u32x4*)(Elo_s + (s3 << 6) + l * 8) = rEl1;
      }
      __syncthreads();  // A for trip t+1
    }
  }
  attn_out(accH, lsH, out, bh, i0hi, lr, lq);
  attn_out(accL, lsL, out, bh, i0lo, lr, lq);
}

// ---------------- host ----------------
extern "C" void kernel_launch(void* const* d_in, const int* in_sizes, int n_in,
                              void* d_out, int out_size, void* d_ws, size_t ws_size,
                              hipStream_t stream) {
  const float* x    = (const float*)d_in[0];
  const float* wq   = (const float*)d_in[2];
  const float* wk   = (const float*)d_in[3];
  const float* wv   = (const float*)d_in[4];
  const float* w0   = (const float*)d_in[5];
  const float* b0   = (const float*)d_in[6];
  const float* rel  = (const float*)d_in[7];
  const float* ln1g = (const float*)d_in[8];
  const float* ln1b = (const float*)d_in[9];
  const float* ln2g = (const float*)d_in[10];
  const float* ln2b = (const float*)d_in[11];
  const float* fw1  = (const float*)d_in[12];
  const float* fb1  = (const float*)d_in[13];
  const float* fw2  = (const float*)d_in[14];
  const float* fb2  = (const float*)d_in[15];
  float* outp = (float*)d_out;

  char* ws = (char*)d_ws;
  size_t off = 0;
  auto alloc = [&](size_t bytes) {
    char* p = ws + off;
    off += (bytes + 255) & ~(size_t)255;
    return p;
  };
  short* wqkvT = (short*)alloc((size_t)1536 * 512 * 2);  // contiguous with w0T
  short* w0T   = (short*)alloc((size_t)512 * 512 * 2);   // == wqkvT + 3*512*512
  short* fw1T  = (short*)alloc((size_t)2048 * 512 * 2);
  short* fw2T  = (short*)alloc((size_t)512 * 2048 * 2);
  short* relb  = (short*)alloc((size_t)8 * 2048 * 64 * 2);
  short* hbuf  = (short*)alloc((size_t)8192 * 512 * 2);
  short* Qb    = (short*)alloc((size_t)8192 * 512 * 2);
  short* Kbf   = (short*)alloc((size_t)8192 * 512 * 2);
  short* VTb   = (short*)alloc((size_t)8192 * 512 * 2);
  short* attnb = (short*)alloc((size_t)8192 * 512 * 2);
  float* x2    = (float*)alloc((size_t)8192 * 512 * 4);
  short* ff1 = hbuf;          // FF1 output aliases h (dead after QKV gemm)
  short* h2  = attnb;         // h2 aliases attn output (dead after O-proj)
  (void)w0T;

  dim3 blk(256);
  // merged prep: rel conv vectorized (1024) + 4x512^2 transpose (256) +
  // fw1 (256) + fw2 (256) + LN1 (2048) = 3840 blocks, one launch
  prep_kernel<<<3840, blk, 0, stream>>>(rel, relb, wq, wk, wv, w0, wqkvT,
                                        fw1, fw1T, fw2, fw2T,
                                        x, ln1g, ln1b, hbuf);
  gemm_kernel<512, 0><<<dim3(12, 64), blk, 0, stream>>>(hbuf, wqkvT, nullptr, nullptr,
                                                        Qb, Kbf, VTb, nullptr);
  attn_kernel<<<512, blk, 0, stream>>>(Qb, Kbf, VTb, relb, attnb);
  gemm64_kernel<512><<<dim3(8, 64), blk, 0, stream>>>(attnb, wqkvT + (size_t)3 * 512 * 512,
                                                      b0, x, x2);
  ln_kernel<<<2048, blk, 0, stream>>>(x2, ln2g, ln2b, h2);
  gemm_kernel<512, 2><<<dim3(16, 64), blk, 0, stream>>>(h2, fw1T, fb1, nullptr,
                                                        ff1, nullptr, nullptr, nullptr);
  gemm64_kernel<2048><<<dim3(8, 64), blk, 0, stream>>>(ff1, fw2T, fb2, x2, outp);
}

// Round 24
// 195.739 us; speedup vs baseline: 1.1510x; 1.0359x over previous
//
#include <hip/hip_runtime.h>
#include <hip/hip_bf16.h>

// Problem constants
#define SB 2048
#define DB 512
#define HB 8
#define DKB 64
#define DFB 2048
#define BATCH 4
#define BSTR 92   // band/P LDS row stride in shorts (184B: 14 dw mod 32, gcd 2)

typedef __attribute__((ext_vector_type(8))) short bf16x8;
typedef __attribute__((ext_vector_type(4))) float f32x4;
typedef __attribute__((ext_vector_type(2))) float f32x2;
typedef __attribute__((ext_vector_type(2))) unsigned u32x2;
typedef __attribute__((ext_vector_type(4))) unsigned u32x4;
typedef __attribute__((ext_vector_type(4))) short s16x4;

static __device__ __forceinline__ short f2bf(float x) {
  union { float f; unsigned u; } v; v.f = x;
  unsigned r = (v.u + 0x7fffu + ((v.u >> 16) & 1u)) >> 16;
  return (short)(unsigned short)r;
}

static __device__ __forceinline__ float bflo(unsigned u) {
  union { unsigned x; float f; } v; v.x = u << 16; return v.f;
}
static __device__ __forceinline__ float bfhi(unsigned u) {
  union { unsigned x; float f; } v; v.x = u & 0xffff0000u; return v.f;
}

static __device__ __forceinline__ unsigned pack2bf(float a, float b) {
  return (unsigned)(unsigned short)f2bf(a) | ((unsigned)(unsigned short)f2bf(b) << 16);
}

static __device__ __forceinline__ f32x4 mfma16(bf16x8 a, bf16x8 b, f32x4 c) {
  return __builtin_amdgcn_mfma_f32_16x16x32_bf16(a, b, c, 0, 0, 0);
}

// raw hardware 2^x (v_exp_f32); exp2f() is the precise libm path (R16 regr.)
static __device__ __forceinline__ float fexp2(float x) {
#if __has_builtin(__builtin_amdgcn_exp2f)
  return __builtin_amdgcn_exp2f(x);
#else
  float r;
  asm("v_exp_f32 %0, %1" : "=v"(r) : "v"(x));
  return r;
#endif
}

// async global->LDS, 16B per lane; LDS dest is wave-uniform base + lane*16
static __device__ __forceinline__ void gload_lds16(const short* g, short* l) {
  __builtin_amdgcn_global_load_lds(
      (const __attribute__((address_space(1))) unsigned*)g,
      (__attribute__((address_space(3))) unsigned*)l, 16, 0, 0);
}

// ---------------- merged prep: rel-conv (float4-vectorized) + 4x weight
// transpose + fw1/fw2 transpose + LN1, one launch.
__global__ __launch_bounds__(256) void prep_kernel(
    const float* __restrict__ rel, short* __restrict__ relb,
    const float* __restrict__ wq, const float* __restrict__ wk,
    const float* __restrict__ wv, const float* __restrict__ w0,
    short* __restrict__ wqkvT,
    const float* __restrict__ fw1, short* __restrict__ fw1T,
    const float* __restrict__ fw2, short* __restrict__ fw2T,
    const float* __restrict__ x, const float* __restrict__ ln1g,
    const float* __restrict__ ln1b, short* __restrict__ hbuf) {
  __shared__ float t[64][65];
  int b = blockIdx.x;
  int tid = threadIdx.x;
  if (b < 1024) {
    // rel conv vectorized: 1048576 floats = 1024 blocks * 256 thr * 4 elems
    int i = (b * 256 + tid) * 4;
    f32x4 v = *(const f32x4*)(rel + i);
    s16x4 o;
#pragma unroll
    for (int e = 0; e < 4; ++e) o[e] = f2bf(v[e]);
    *(s16x4*)(relb + i) = o;
  } else if (b < 1792) {
    const float* src;
    short* dst;
    int K, N, n0, k0;
    float scale = 1.f;
    if (b < 1280) {  // wq/wk/wv/w0 (512x512), 64 blocks each
      int idx = b - 1024;
      int z = idx >> 6;
      src = z == 0 ? wq : (z == 1 ? wk : (z == 2 ? wv : w0));
      scale = (z == 0) ? 1.4426950408889634f : ((z == 1) ? 0.125f : 1.f);
      dst = wqkvT + (size_t)z * 512 * 512;
      K = 512; N = 512;
      n0 = (idx & 7) * 64;
      k0 = ((idx >> 3) & 7) * 64;
    } else if (b < 1536) {  // fw1: K=512, N=2048
      int idx = b - 1280;
      src = fw1; dst = fw1T; K = 512; N = 2048;
      n0 = (idx & 31) * 64;
      k0 = (idx >> 5) * 64;
    } else {                // fw2: K=2048, N=512
      int idx = b - 1536;
      src = fw2; dst = fw2T; K = 2048; N = 512;
      n0 = (idx & 7) * 64;
      k0 = (idx >> 3) * 64;
    }
    int cn = tid & 63, rk = tid >> 6;
#pragma unroll
    for (int r = 0; r < 16; ++r)
      t[rk + r * 4][cn] = src[(size_t)(k0 + rk + r * 4) * N + n0 + cn];
    __syncthreads();
#pragma unroll
    for (int r = 0; r < 16; ++r)
      dst[(size_t)(n0 + rk + r * 4) * K + k0 + cn] = f2bf(t[cn][rk + r * 4] * scale);
  } else {
    // LN1: one wave per 512-elem row, 2048 blocks
    int idx = b - 1792;
    int w = tid >> 6, l = tid & 63;
    size_t row = (size_t)idx * 4 + w;
    const float* xr = x + row * DB;
    f32x4 v0 = *(const f32x4*)(xr + l * 8);
    f32x4 v1 = *(const f32x4*)(xr + l * 8 + 4);
    float s = (v0[0] + v0[1]) + (v0[2] + v0[3]) + (v1[0] + v1[1]) + (v1[2] + v1[3]);
    float s2 = (v0[0] * v0[0] + v0[1] * v0[1]) + (v0[2] * v0[2] + v0[3] * v0[3]) +
               (v1[0] * v1[0] + v1[1] * v1[1]) + (v1[2] * v1[2] + v1[3] * v1[3]);
#pragma unroll
    for (int off = 1; off < 64; off <<= 1) {
      s += __shfl_xor(s, off, 64);
      s2 += __shfl_xor(s2, off, 64);
    }
    float mean = s * (1.f / DB);
    float var = s2 * (1.f / DB) - mean * mean;
    float rstd = rsqrtf(var + 1e-6f);
    f32x4 g0 = *(const f32x4*)(ln1g + l * 8);
    f32x4 g1 = *(const f32x4*)(ln1g + l * 8 + 4);
    f32x4 b0 = *(const f32x4*)(ln1b + l * 8);
    f32x4 b1 = *(const f32x4*)(ln1b + l * 8 + 4);
    bf16x8 ov;
#pragma unroll
    for (int e = 0; e < 4; ++e) ov[e] = f2bf((v0[e] - mean) * rstd * g0[e] + b0[e]);
#pragma unroll
    for (int e = 0; e < 4; ++e) ov[4 + e] = f2bf((v1[e] - mean) * rstd * g1[e] + b1[e]);
    *(bf16x8*)(hbuf + row * DB + l * 8) = ov;
  }
}

// ---------------- layernorm (LN2): one wave per 512-elem row --------------
__global__ __launch_bounds__(256) void ln_kernel(const float* __restrict__ in,
                                                 const float* __restrict__ g,
                                                 const float* __restrict__ bb,
                                                 short* __restrict__ out) {
  int w = threadIdx.x >> 6, l = threadIdx.x & 63;
  size_t row = (size_t)blockIdx.x * 4 + w;
  const float* xr = in + row * DB;
  f32x4 v0 = *(const f32x4*)(xr + l * 8);
  f32x4 v1 = *(const f32x4*)(xr + l * 8 + 4);
  float s = (v0[0] + v0[1]) + (v0[2] + v0[3]) + (v1[0] + v1[1]) + (v1[2] + v1[3]);
  float s2 = (v0[0] * v0[0] + v0[1] * v0[1]) + (v0[2] * v0[2] + v0[3] * v0[3]) +
             (v1[0] * v1[0] + v1[1] * v1[1]) + (v1[2] * v1[2] + v1[3] * v1[3]);
#pragma unroll
  for (int off = 1; off < 64; off <<= 1) {
    s += __shfl_xor(s, off, 64);
    s2 += __shfl_xor(s2, off, 64);
  }
  float mean = s * (1.f / DB);
  float var = s2 * (1.f / DB) - mean * mean;
  float rstd = rsqrtf(var + 1e-6f);
  f32x4 g0 = *(const f32x4*)(g + l * 8);
  f32x4 g1 = *(const f32x4*)(g + l * 8 + 4);
  f32x4 b0 = *(const f32x4*)(bb + l * 8);
  f32x4 b1 = *(const f32x4*)(bb + l * 8 + 4);
  bf16x8 ov;
#pragma unroll
  for (int e = 0; e < 4; ++e) ov[e] = f2bf((v0[e] - mean) * rstd * g0[e] + b0[e]);
#pragma unroll
  for (int e = 0; e < 4; ++e) ov[4 + e] = f2bf((v1[e] - mean) * rstd * g1[e] + b1[e]);
  *(bf16x8*)(out + row * DB + l * 8) = ov;
}

// ---------------- GEMM 128x128, BK=32 dbuf + 4-chunk swizzle + T1 XCD -----
template <int KD, int EPI>
__global__ __launch_bounds__(256) void gemm_kernel(
    const short* __restrict__ A, const short* __restrict__ BT,
    const float* __restrict__ bias, const float* __restrict__ resid,
    short* __restrict__ o0, short* __restrict__ o1, short* __restrict__ o2,
    float* __restrict__ of) {
  __shared__ short As[2][4096];  // 128 rows x 32 k
  __shared__ short Bs[2][4096];
  int tid = threadIdx.x;
  int l = tid & 63, w = tid >> 6;
  int wr = w >> 1, wc = w & 1;
  int lr = l & 15, lq = l >> 4;
  int nwgx = gridDim.x;
  int flat = blockIdx.y * nwgx + blockIdx.x;
  int nwg = nwgx * gridDim.y;                    // divisible by 8
  int wid = (flat & 7) * (nwg >> 3) + (flat >> 3);
  int row0 = (wid / nwgx) * 128;
  int col0 = (wid % nwgx) * 128;

  f32x4 acc[4][4];
#pragma unroll
  for (int a = 0; a < 4; ++a)
#pragma unroll
    for (int b = 0; b < 4; ++b) acc[a][b] = (f32x4){0.f, 0.f, 0.f, 0.f};

  int srow = tid >> 2;                   // [0,64); also stages srow+64
  int scol = (tid & 3) ^ (srow & 3);     // inverse-swizzled source chunk
  const short* gA = A + (size_t)(row0 + srow) * KD + scol * 8;
  const short* gB = BT + (size_t)(col0 + srow) * KD + scol * 8;
  const size_t step64 = (size_t)64 * KD;
  int woff = w * 512;

  auto stage = [&](int buf, int k0) {
    gload_lds16(gA + k0, As[buf] + woff);
    gload_lds16(gA + step64 + k0, As[buf] + woff + 2048);
    gload_lds16(gB + k0, Bs[buf] + woff);
    gload_lds16(gB + step64 + k0, Bs[buf] + woff + 2048);
  };

  stage(0, 0);
  __syncthreads();
  int cur = 0;
  for (int k0 = 0; k0 < KD; k0 += 32) {
    if (k0 + 32 < KD) stage(cur ^ 1, k0 + 32);  // prefetch next tile
    bf16x8 af[4], bfv[4];
#pragma unroll
    for (int a = 0; a < 4; ++a) {
      int rk = wr * 64 + a * 16 + lr;
      af[a] = *(const bf16x8*)(As[cur] + rk * 32 + ((lq ^ (rk & 3)) << 3));
    }
#pragma unroll
    for (int b = 0; b < 4; ++b) {
      int rk = wc * 64 + b * 16 + lr;
      bfv[b] = *(const bf16x8*)(Bs[cur] + rk * 32 + ((lq ^ (rk & 3)) << 3));
    }
#pragma unroll
    for (int a = 0; a < 4; ++a)
#pragma unroll
      for (int b = 0; b < 4; ++b)
        acc[a][b] = mfma16(af[a], bfv[b], acc[a][b]);
    __syncthreads();
    cur ^= 1;
  }

#pragma unroll
  for (int a = 0; a < 4; ++a)
#pragma unroll
    for (int b = 0; b < 4; ++b) {
      size_t colb = (size_t)col0 + wc * 64 + b * 16 + lr;
      if (EPI == 0 && (int)(colb >> 9) == 2) {
        int d = (int)(colb & 63);
        size_t rowb = (size_t)row0 + wr * 64 + a * 16 + lq * 4;
        size_t b_ = rowb >> 11, s_ = rowb & 2047;
        size_t bh = b_ * HB + (int)((colb >> 6) & 7);
        s16x4 pkv;
#pragma unroll
        for (int r = 0; r < 4; ++r) pkv[r] = f2bf(acc[a][b][r]);
        *(s16x4*)(o2 + (bh * DKB + d) * SB + s_) = pkv;
        continue;
      }
#pragma unroll
      for (int r = 0; r < 4; ++r) {
        size_t row = (size_t)row0 + wr * 64 + a * 16 + lq * 4 + r;
        size_t col = colb;
        float val = acc[a][b][r];
        if (EPI == 0) {
          int sect = (int)(col >> 9);
          int hh = (int)((col >> 6) & 7);
          int d = (int)(col & 63);
          size_t b_ = row >> 11, s_ = row & 2047;
          size_t bh = b_ * HB + hh;
          short bv = f2bf(val);
          if (sect == 0) o0[(bh * SB + s_) * DKB + d] = bv;
          else o1[(bh * SB + s_) * DKB + d] = bv;
        } else if (EPI == 1) {
          of[row * DB + col] = resid[row * DB + col] + val + bias[col];
        } else {
          float tv = val + bias[col];
          o0[row * DFB + col] = f2bf(tv > 0.f ? tv : 0.f);
        }
      }
    }
}

// ---------------- GEMM 64x64, BK=32 dbuf + swizzle + T1 XCD (O-proj/FF2) --
// BM=64 -> grid 1024 blocks = 4 blocks/CU: per-step vmcnt drains of the 64
// (FF2) serialized K-steps overlap across twice as many co-resident blocks.
// 4 waves, each 16 rows x 64 cols (4 MFMA/step). LDS 16KB.
template <int KD>
__global__ __launch_bounds__(256) void gemm64_kernel(
    const short* __restrict__ A, const short* __restrict__ BT,
    const float* __restrict__ bias, const float* __restrict__ resid,
    float* __restrict__ of) {
  __shared__ short As[2][2048];  // 64 rows x 32 k
  __shared__ short Bs[2][2048];  // 64 cols x 32 k
  int tid = threadIdx.x;
  int l = tid & 63, w = tid >> 6;
  int lr = l & 15, lq = l >> 4;
  int nwgx = gridDim.x;
  int flat = blockIdx.y * nwgx + blockIdx.x;
  int nwg = nwgx * gridDim.y;                    // divisible by 8
  int wid = (flat & 7) * (nwg >> 3) + (flat >> 3);
  int row0 = (wid / nwgx) * 64;
  int col0 = (wid % nwgx) * 64;

  f32x4 acc[4];
#pragma unroll
  for (int b = 0; b < 4; ++b) acc[b] = (f32x4){0.f, 0.f, 0.f, 0.f};

  int srow = tid >> 2;                   // [0,64)
  int scol = (tid & 3) ^ (srow & 3);     // inverse-swizzled source chunk
  const short* gA = A + (size_t)(row0 + srow) * KD + scol * 8;
  const short* gB = BT + (size_t)(col0 + srow) * KD + scol * 8;
  int woff = w * 512;

  auto stage = [&](int buf, int k0) {
    gload_lds16(gA + k0, As[buf] + woff);
    gload_lds16(gB + k0, Bs[buf] + woff);
  };

  stage(0, 0);
  __syncthreads();
  int cur = 0;
  for (int k0 = 0; k0 < KD; k0 += 32) {
    if (k0 + 32 < KD) stage(cur ^ 1, k0 + 32);
    bf16x8 af;
    {
      int rk = w * 16 + lr;
      af = *(const bf16x8*)(As[cur] + rk * 32 + ((lq ^ (rk & 3)) << 3));
    }
    bf16x8 bfv[4];
#pragma unroll
    for (int b = 0; b < 4; ++b) {
      int rk = b * 16 + lr;
      bfv[b] = *(const bf16x8*)(Bs[cur] + rk * 32 + ((lq ^ (rk & 3)) << 3));
    }
#pragma unroll
    for (int b = 0; b < 4; ++b)
      acc[b] = mfma16(af, bfv[b], acc[b]);
    __syncthreads();
    cur ^= 1;
  }

#pragma unroll
  for (int b = 0; b < 4; ++b)
#pragma unroll
    for (int r = 0; r < 4; ++r) {
      size_t row = (size_t)row0 + w * 16 + lq * 4 + r;
      size_t col = (size_t)col0 + b * 16 + lr;
      of[row * DB + col] = resid[row * DB + col] + acc[b][r] + bias[col];
    }
}

// ---------------- attention helpers ----------------
static __device__ __forceinline__ void e_phase_lds(const short* Ebuf, int w, int ph,
                                                   bf16x8 q0, bf16x8 q1,
                                                   short* bdx, int lr, int lq) {
  bf16x8 ef[10];
#pragma unroll
  for (int nt = 0; nt < 5; ++nt) {
    int re = 48 - 16 * w + nt * 16 + lr;
    int sr = (re + ph) & 127;
    const short* eb = Ebuf + sr * 64;
    ef[nt * 2] = *(const bf16x8*)(eb + ((lq ^ (sr & 7)) << 3));
    ef[nt * 2 + 1] = *(const bf16x8*)(eb + (((lq + 4) ^ (sr & 7)) << 3));
  }
  const f32x4 zz = {0.f, 0.f, 0.f, 0.f};
#pragma unroll
  for (int nt = 0; nt < 5; ++nt) {
    f32x4 rr = mfma16(ef[nt * 2 + 1], q1, mfma16(ef[nt * 2], q0, zz));
    u32x2 pk = {pack2bf(rr[0], rr[1]), pack2bf(rr[2], rr[3])};
    *(u32x2*)((char*)bdx + lr * (BSTR * 2) + (nt * 16 + lq * 4) * 2) = pk;
  }
}

// Defer-max softmax (2^x via raw v_exp; Q carries log2e). Vector band gather.
static __device__ __forceinline__ void sm_step(const f32x4* sc, const short* bd,
                                               short* pb, f32x4* acc,
                                               float& mrun, float& lsum,
                                               int i0, int j0, int lr, int lq) {
  int bbase = lq * 4 + 15 - lr;
  int o = bbase & 3;
  unsigned shb = (unsigned)(o & 1) * 16;
  bool hi2 = (o >= 2);
  float bv[4][4];
#pragma unroll
  for (int hh = 0; hh < 4; ++hh) {
    int w0 = (hh * 16 + bbase) & ~3;
    const unsigned* p = (const unsigned*)(bd + lr * BSTR + w0);
    unsigned W0 = p[0], W1 = p[1], W2 = p[2], W3 = p[3];
    unsigned X0 = hi2 ? W1 : W0;
    unsigned X1 = hi2 ? W2 : W1;
    unsigned X2 = hi2 ? W3 : W2;
    unsigned out0 = (unsigned)((((unsigned long long)X1 << 32) | X0) >> shb);
    unsigned out1 = (unsigned)((((unsigned long long)X2 << 32) | X1) >> shb);
    bv[hh][0] = bflo(out0);
    bv[hh][1] = bfhi(out0);
    bv[hh][2] = bflo(out1);
    bv[hh][3] = bfhi(out1);
  }
  float s[4][4];
  if (j0 + 63 > i0) {
    int thr = i0 + lr - j0;
#pragma unroll
    for (int hh = 0; hh < 4; ++hh)
#pragma unroll
      for (int r = 0; r < 4; ++r) {
        int n = hh * 16 + lq * 4 + r;
        float v = sc[hh][r] + bv[hh][r];
        s[hh][r] = (n <= thr) ? v : -1e30f;
      }
  } else {
#pragma unroll
    for (int hh = 0; hh < 4; ++hh)
#pragma unroll
      for (int r = 0; r < 4; ++r) s[hh][r] = sc[hh][r] + bv[hh][r];
  }
  float m0 = fmaxf(fmaxf(s[0][0], s[0][1]), fmaxf(s[0][2], s[0][3]));
  float m1 = fmaxf(fmaxf(s[1][0], s[1][1]), fmaxf(s[1][2], s[1][3]));
  float m2 = fmaxf(fmaxf(s[2][0], s[2][1]), fmaxf(s[2][2], s[2][3]));
  float m3 = fmaxf(fmaxf(s[3][0], s[3][1]), fmaxf(s[3][2], s[3][3]));
  float tm = fmaxf(fmaxf(m0, m1), fmaxf(m2, m3));
  if (!__all(tm <= mrun + 8.f)) {
    float tr = fmaxf(tm, __shfl_xor(tm, 16, 64));
    tr = fmaxf(tr, __shfl_xor(tr, 32, 64));
    float mnew = fmaxf(mrun, tr);
    float corr = fexp2(mrun - mnew);
    mrun = mnew;
    lsum *= corr;
#pragma unroll
    for (int dt = 0; dt < 4; ++dt) acc[dt] *= corr;
  }
#pragma unroll
  for (int hh = 0; hh < 4; ++hh) {
    float p0 = fexp2(s[hh][0] - mrun);
    float p1 = fexp2(s[hh][1] - mrun);
    float p2 = fexp2(s[hh][2] - mrun);
    float p3 = fexp2(s[hh][3] - mrun);
    lsum += (p0 + p1) + (p2 + p3);
    u32x2 pk = {pack2bf(p0, p1), pack2bf(p2, p3)};
    int byteoff = lr * (BSTR * 2) + ((((hh << 1) | (lq >> 1)) ^ (lr & 7)) << 4) + ((lq & 1) << 3);
    *(u32x2*)((char*)pb + byteoff) = pk;
  }
}

static __device__ __forceinline__ void pv_step(const short* pb, const bf16x8* vf,
                                               f32x4* acc, int lr, int lq) {
#pragma unroll
  for (int kc = 0; kc < 2; ++kc) {
    bf16x8 pf = *(const bf16x8*)((const char*)pb + lr * (BSTR * 2) +
                                 ((((kc << 2) | lq) ^ (lr & 7)) << 4));
    __builtin_amdgcn_s_setprio(1);
#pragma unroll
    for (int dt = 0; dt < 4; ++dt)
      acc[dt] = mfma16(vf[kc * 4 + dt], pf, acc[dt]);
    __builtin_amdgcn_s_setprio(0);
  }
}

static __device__ __forceinline__ void attn_out(const f32x4* acc, float lsum,
                                                short* out, int bh, int i0,
                                                int lr, int lq) {
  float lt = lsum + __shfl_xor(lsum, 16, 64);
  lt += __shfl_xor(lt, 32, 64);
  float inv = 1.f / lt;
  int b_ = bh >> 3, hd = bh & 7;
  short* orow = out + ((size_t)(b_ * SB + i0 + lr) * DB + hd * 64);
#pragma unroll
  for (int dt = 0; dt < 4; ++dt) {
    s16x4 pkv;
#pragma unroll
    for (int r = 0; r < 4; ++r) pkv[r] = f2bf(acc[dt][r] * inv);
    *(s16x4*)(orow + dt * 16 + lq * 4) = pkv;
  }
}

// ---------------- fused causal attention with relative positions ----------
// R18/R20 structure: block-cooperative staging, E rings, T14 reg prefetch.
__global__ __launch_bounds__(256, 2) void attn_kernel(
    const short* __restrict__ Q, const short* __restrict__ Kb,
    const short* __restrict__ VT, const short* __restrict__ Eb,
    short* __restrict__ out) {
  __shared__ short Ks[4096];
  __shared__ short Vs[4096];
  __shared__ short Elo_s[8192];     // 128-row ring
  __shared__ short Ehi_s[8192];     // 128-row ring
  __shared__ short bandP[4][2][16][BSTR];
  int tid = threadIdx.x;
  int l = tid & 63, w = tid >> 6;
  int lr = l & 15, lq = l >> 4;
  int bid = blockIdx.x;                  // 512 blocks
  int s = bid >> 3;                      // [0,64)
  int bh = (bid & 7) * 4 + (s >> 4);     // 4 heads per XCD slot
  int g = s & 15;
  int qb0 = g << 6;
  int qb1 = (31 - g) << 6;
  int i0lo = qb0 + (w << 4);
  int i0hi = qb1 + (w << 4);
  const short* Qh = Q + (size_t)bh * SB * DKB;
  const short* Kh = Kb + (size_t)bh * SB * DKB;
  const short* Vh = VT + (size_t)bh * DKB * SB;
  const short* Eh = Eb + (size_t)(bh & 7) * SB * DKB;

  bf16x8 ql0 = *(const bf16x8*)(Qh + (size_t)(i0lo + lr) * DKB + lq * 8);
  bf16x8 ql1 = *(const bf16x8*)(Qh + (size_t)(i0lo + lr) * DKB + 32 + lq * 8);
  bf16x8 qh0 = *(const bf16x8*)(Qh + (size_t)(i0hi + lr) * DKB + lq * 8);
  bf16x8 qh1 = *(const bf16x8*)(Qh + (size_t)(i0hi + lr) * DKB + 32 + lq * 8);

  int lrow = l >> 3, lch = l & 7;
  int rKV = (w << 4) + lrow;
  int cKV = lch ^ (rKV & 7);
  int cE = lch ^ lrow;                   // E swizzle: slot&7 == lrow

  const f32x4 zz = {0.f, 0.f, 0.f, 0.f};
  f32x4 accL[4], accH[4];
#pragma unroll
  for (int dt = 0; dt < 4; ++dt) { accL[dt] = zz; accH[dt] = zz; }
  float mL = -1e30f, lsL = 0.f, mH = -1e30f, lsH = 0.f;
  short* bdL = &bandP[w][0][0][0];
  short* bdH = &bandP[w][1][0][0];

  int ntrips = (qb1 >> 6) + 1;

  // ---- prologue: stage trip 0 fully via global_load_lds ----
  {
    gload_lds16(Kh + (size_t)rKV * DKB + cKV * 8, Ks + (w << 10));
    gload_lds16(Kh + (size_t)(rKV + 8) * DKB + cKV * 8, Ks + (w << 10) + 512);
    gload_lds16(Vh + (size_t)rKV * SB + cKV * 8, Vs + (w << 10));
    gload_lds16(Vh + (size_t)(rKV + 8) * SB + cKV * 8, Vs + (w << 10) + 512);
    int rbHi0 = SB - 64 - qb1;
    int phHi0 = rbHi0 & 64;
#pragma unroll
    for (int ii = 0; ii < 4; ++ii) {
      int er = rbHi0 + (w << 5) + lrow + ii * 8;
      er = er < SB ? er : SB - 1;
      int slot0 = ((w << 5) + ii * 8 + phHi0) & 127;
      gload_lds16(Eh + (size_t)er * DKB + cE * 8, Ehi_s + (slot0 << 6));
    }
    int rbLo0 = SB - 64 - qb0;
    int phLo0 = rbLo0 & 64;
#pragma unroll
    for (int ii = 0; ii < 4; ++ii) {
      int er = rbLo0 + (w << 5) + lrow + ii * 8;
      er = er < SB ? er : SB - 1;
      int slot0 = ((w << 5) + ii * 8 + phLo0) & 127;
      gload_lds16(Eh + (size_t)er * DKB + cE * 8, Elo_s + (slot0 << 6));
    }
  }
  __syncthreads();

  u32x4 rK0, rK1, rV0, rV1, rEh0, rEh1, rEl0, rEl1;

  for (int t = 0; t < ntrips; ++t) {
    int j0 = t << 6;
    int phHi = (SB - 64 - qb1 + j0) & 64;
    int phLo = (SB - 64 - qb0 + j0) & 64;
    bool pf = (t + 1 < ntrips);
    bool pfLo = (t + 1 <= g);
    // ---- issue prefetch loads for t+1 (pinned early by sched_barrier) ----
    if (pf) {
      int j0n = j0 + 64;
      rK0 = *(const u32x4*)(Kh + (size_t)(j0n + rKV) * DKB + cKV * 8);
      rK1 = *(const u32x4*)(Kh + (size_t)(j0n + rKV + 8) * DKB + cKV * 8);
      rV0 = *(const u32x4*)(Vh + (size_t)rKV * SB + j0n + cKV * 8);
      rV1 = *(const u32x4*)(Vh + (size_t)(rKV + 8) * SB + j0n + cKV * 8);
      int eb0 = SB - 64 - qb1 + j0 + 128 + (w << 4) + lrow;  // t+1 new half
      int e0 = eb0 < SB ? eb0 : SB - 1;
      int e1 = (eb0 + 8) < SB ? (eb0 + 8) : SB - 1;
      rEh0 = *(const u32x4*)(Eh + (size_t)e0 * DKB + cE * 8);
      rEh1 = *(const u32x4*)(Eh + (size_t)e1 * DKB + cE * 8);
      if (pfLo) {
        int fb0 = SB - 64 - qb0 + j0 + 128 + (w << 4) + lrow;
        int f0 = fb0 < SB ? fb0 : SB - 1;
        int f1 = (fb0 + 8) < SB ? (fb0 + 8) : SB - 1;
        rEl0 = *(const u32x4*)(Eh + (size_t)f0 * DKB + cE * 8);
        rEl1 = *(const u32x4*)(Eh + (size_t)f1 * DKB + cE * 8);
      }
    }
    __builtin_amdgcn_sched_barrier(0);  // pin load ISSUE above all compute
    // ---- compute trip t ----
    bool actLo = (t <= g);
    {
      bf16x8 kf[8];
#pragma unroll
      for (int hh = 0; hh < 4; ++hh) {
        int rk = hh * 16 + lr;
        const short* kb = Ks + rk * 64;
        kf[hh * 2] = *(const bf16x8*)(kb + ((lq ^ (rk & 7)) << 3));
        kf[hh * 2 + 1] = *(const bf16x8*)(kb + (((lq + 4) ^ (rk & 7)) << 3));
      }
      f32x4 scH[4], scL[4];
#pragma unroll
      for (int hh = 0; hh < 4; ++hh)
        scH[hh] = mfma16(kf[hh * 2 + 1], qh1, mfma16(kf[hh * 2], qh0, zz));
      if (actLo) {
#pragma unroll
        for (int hh = 0; hh < 4; ++hh)
          scL[hh] = mfma16(kf[hh * 2 + 1], ql1, mfma16(kf[hh * 2], ql0, zz));
      }
      bf16x8 vf[8];
#pragma unroll
      for (int kc = 0; kc < 2; ++kc)
#pragma unroll
        for (int dt = 0; dt < 4; ++dt) {
          int rv = dt * 16 + lr;
          vf[kc * 4 + dt] = *(const bf16x8*)(Vs + rv * 64 +
                                             (((kc * 4 + lq) ^ (rv & 7)) << 3));
        }
      e_phase_lds(Ehi_s, w, phHi, qh0, qh1, bdH, lr, lq);
      if (actLo) e_phase_lds(Elo_s, w, phLo, ql0, ql1, bdL, lr, lq);
      sm_step(scH, bdH, bdH, accH, mH, lsH, i0hi, j0, lr, lq);
      if (actLo) sm_step(scL, bdL, bdL, accL, mL, lsL, i0lo, j0, lr, lq);
      pv_step(bdH, vf, accH, lr, lq);
      if (actLo) pv_step(bdL, vf, accL, lr, lq);
    }
    // ---- write prefetched data between barriers ----
    if (pf) {
      __syncthreads();  // B: all reads of trip t done
      *(u32x4*)(Ks + (w << 10) + l * 8) = rK0;
      *(u32x4*)(Ks + (w << 10) + 512 + l * 8) = rK1;
      *(u32x4*)(Vs + (w << 10) + l * 8) = rV0;
      *(u32x4*)(Vs + (w << 10) + 512 + l * 8) = rV1;
      int s0 = ((w << 4) + phHi) & 127;        // slot of (row & 127) for t+1
      int s1 = ((w << 4) + 8 + phHi) & 127;
      *(u32x4*)(Ehi_s + (s0 << 6) + l * 8) = rEh0;
      *(u32x4*)(Ehi_s + (s1 << 6) + l * 8) = rEh1;
      if (pfLo) {
        int s2 = ((w << 4) + phLo) & 127;
        int s3 = ((w << 4) + 8 + phLo) & 127;
        *(u32x4*)(Elo_s + (s2 << 6) + l * 8) = rEl0;
        *(u32x4*)(Elo_s + (s3 << 6) + l * 8) = rEl1;
      }
      __syncthreads();  // A for trip t+1
    }
  }
  attn_out(accH, lsH, out, bh, i0hi, lr, lq);
  attn_out(accL, lsL, out, bh, i0lo, lr, lq);
}

// ---------------- host ----------------
extern "C" void kernel_launch(void* const* d_in, const int* in_sizes, int n_in,
                              void* d_out, int out_size, void* d_ws, size_t ws_size,
                              hipStream_t stream) {
  const float* x    = (const float*)d_in[0];
  const float* wq   = (const float*)d_in[2];
  const float* wk   = (const float*)d_in[3];
  const float* wv   = (const float*)d_in[4];
  const float* w0   = (const float*)d_in[5];
  const float* b0   = (const float*)d_in[6];
  const float* rel  = (const float*)d_in[7];
  const float* ln1g = (const float*)d_in[8];
  const float* ln1b = (const float*)d_in[9];
  const float* ln2g = (const float*)d_in[10];
  const float* ln2b = (const float*)d_in[11];
  const float* fw1  = (const float*)d_in[12];
  const float* fb1  = (const float*)d_in[13];
  const float* fw2  = (const float*)d_in[14];
  const float* fb2  = (const float*)d_in[15];
  float* outp = (float*)d_out;

  char* ws = (char*)d_ws;
  size_t off = 0;
  auto alloc = [&](size_t bytes) {
    char* p = ws + off;
    off += (bytes + 255) & ~(size_t)255;
    return p;
  };
  short* wqkvT = (short*)alloc((size_t)1536 * 512 * 2);  // contiguous with w0T
  short* w0T   = (short*)alloc((size_t)512 * 512 * 2);   // == wqkvT + 3*512*512
  short* fw1T  = (short*)alloc((size_t)2048 * 512 * 2);
  short* fw2T  = (short*)alloc((size_t)512 * 2048 * 2);
  short* relb  = (short*)alloc((size_t)8 * 2048 * 64 * 2);
  short* hbuf  = (short*)alloc((size_t)8192 * 512 * 2);
  short* Qb    = (short*)alloc((size_t)8192 * 512 * 2);
  short* Kbf   = (short*)alloc((size_t)8192 * 512 * 2);
  short* VTb   = (short*)alloc((size_t)8192 * 512 * 2);
  short* attnb = (short*)alloc((size_t)8192 * 512 * 2);
  float* x2    = (float*)alloc((size_t)8192 * 512 * 4);
  short* ff1 = hbuf;          // FF1 output aliases h (dead after QKV gemm)
  short* h2  = attnb;         // h2 aliases attn output (dead after O-proj)
  (void)w0T;

  dim3 blk(256);
  // merged prep: rel conv vectorized (1024) + 4x512^2 transpose (256) +
  // fw1 (256) + fw2 (256) + LN1 (2048) = 3840 blocks, one launch
  prep_kernel<<<3840, blk, 0, stream>>>(rel, relb, wq, wk, wv, w0, wqkvT,
                                        fw1, fw1T, fw2, fw2T,
                                        x, ln1g, ln1b, hbuf);
  gemm_kernel<512, 0><<<dim3(12, 64), blk, 0, stream>>>(hbuf, wqkvT, nullptr, nullptr,
                                                        Qb, Kbf, VTb, nullptr);
  attn_kernel<<<512, blk, 0, stream>>>(Qb, Kbf, VTb, relb, attnb);
  gemm64_kernel<512><<<dim3(8, 128), blk, 0, stream>>>(attnb, wqkvT + (size_t)3 * 512 * 512,
                                                       b0, x, x2);
  ln_kernel<<<2048, blk, 0, stream>>>(x2, ln2g, ln2b, h2);
  gemm_kernel<512, 2><<<dim3(16, 64), blk, 0, stream>>>(h2, fw1T, fb1, nullptr,
                                                        ff1, nullptr, nullptr, nullptr);
  gemm64_kernel<2048><<<dim3(8, 128), blk, 0, stream>>>(ff1, fw2T, fb2, x2, outp);
}